// Round 1
// baseline (8004.482 us; speedup 1.0000x reference)
//
#include <hip/hip_runtime.h>

#define NPIX 4096
#define NT 256

__global__ void ph_zero_kernel(float* out) { out[0] = 0.0f; }

__global__ __launch_bounds__(NT) void ph_pass_kernel(const float* __restrict__ x,
                                                     float* __restrict__ out) {
  __shared__ unsigned key32[NPIX];              // 16 KB: sortable key per pixel
  __shared__ unsigned long long sbuf[NPIX];     // 32 KB: sort buffer, later u16 arrays

  const int blk = blockIdx.x;           // 24 blocks: b(4) x c(3) x pass(2)
  const int b = blk / 6;
  const int rem = blk % 6;
  const int c = (rem >> 1) + 1;         // classes 1..3 (skip background)
  const int pass = rem & 1;             // 0 = sublevel 8-conn (H0), 1 = superlevel 4-conn (H1)
  const float* img = x + (size_t)(b * 4 + c) * NPIX;
  const int tid = threadIdx.x;

  // --- build monotone sortable keys; pass 1 negates values (superlevel) ---
  for (int i = tid; i < NPIX; i += NT) {
    float f = img[i];
    if (pass) f = -f;
    unsigned u = __float_as_uint(f);
    unsigned k = (u & 0x80000000u) ? ~u : (u | 0x80000000u);  // strictly monotone float->u32
    key32[i] = k;
    sbuf[i] = ((unsigned long long)k << 32) | (unsigned)i;    // stable: idx is tiebreak
  }
  __syncthreads();

  // --- bitonic sort ascending: 78 (k,j) stages ---
  for (int k = 2; k <= NPIX; k <<= 1) {
    for (int j = k >> 1; j > 0; j >>= 1) {
      for (int i = tid; i < NPIX; i += NT) {
        int ixj = i ^ j;
        if (ixj > i) {
          unsigned long long va = sbuf[i], vb = sbuf[ixj];
          bool up = ((i & k) == 0);
          if ((va > vb) == up) { sbuf[i] = vb; sbuf[ixj] = va; }
        }
      }
      __syncthreads();
    }
  }

  // --- extract order (u16) into low 8KB of sbuf; carve parent/creator from sbuf ---
  unsigned long long mine[NPIX / NT];
  #pragma unroll
  for (int t = 0; t < NPIX / NT; t++) mine[t] = sbuf[tid + t * NT];
  __syncthreads();
  unsigned short* order   = (unsigned short*)sbuf;   // [0, 8K)
  unsigned short* parent  = order + NPIX;            // [8K, 16K)
  unsigned short* creator = order + 2 * NPIX;        // [16K, 24K)
  #pragma unroll
  for (int t = 0; t < NPIX / NT; t++)
    order[tid + t * NT] = (unsigned short)(mine[t] & 0xFFFFull);
  for (int i = tid; i < NPIX; i += NT) parent[i] = 0xFFFFu;   // sentinel: not in filtration
  __syncthreads();

  // --- serial union-find with path halving (thread 0) ---
  if (tid == 0) {
    const int drr[8] = {-1, 1, 0, 0, -1, -1, 1, 1};
    const int dcc[8] = { 0, 0,-1, 1, -1,  1, -1, 1};
    const int ndirs = pass ? 4 : 8;
    double sumsq = 0.0;
    float maxp = 0.0f;
    int cnt = 0;
    for (int oi = 0; oi < NPIX; oi++) {
      const int idx = order[oi];
      parent[idx]  = (unsigned short)idx;
      creator[idx] = (unsigned short)idx;
      int root = idx;
      const unsigned kidx = key32[idx];
      const int r = idx >> 6, cc = idx & 63;
      for (int d = 0; d < ndirs; d++) {
        const int rr = r + drr[d], c2 = cc + dcc[d];
        if ((unsigned)rr >= 64u || (unsigned)c2 >= 64u) continue;
        const int nb = (rr << 6) | c2;
        if (parent[nb] == 0xFFFFu) continue;   // neighbor not yet in filtration
        // find(nb), path halving
        int a = nb;
        while (true) {
          int p = parent[a];
          if (p == a) break;
          int gp = parent[p];
          parent[a] = (unsigned short)gp;
          a = gp;
        }
        if (a == root) continue;
        const int ra = root, rb = a;
        const int ca = creator[ra], cb = creator[rb];
        const unsigned ka = key32[ca], kb = key32[cb];
        // elder rule: smaller (key, idx) = earlier rank survives
        const bool a_elder = (ka < kb) || (ka == kb && ca < cb);
        const int elder = a_elder ? ra : rb;
        const int young = a_elder ? rb : ra;
        const int cy    = a_elder ? cb : ca;
        const unsigned kcy = key32[cy];
        if (kidx > kcy) {  // strictly positive persistence (key transform is monotone)
          unsigned ui = (kidx & 0x80000000u) ? (kidx & 0x7FFFFFFFu) : ~kidx;
          unsigned uy = (kcy  & 0x80000000u) ? (kcy  & 0x7FFFFFFFu) : ~kcy;
          float pers = __uint_as_float(ui) - __uint_as_float(uy);
          sumsq += (double)pers * (double)pers;
          maxp = fmaxf(maxp, pers);
          cnt++;
        }
        parent[young] = (unsigned short)elder;
        root = elder;
      }
    }

    // --- per-(b,c,pass) loss contribution; nf from TOPO, classes 1..3 ---
    float contrib;
    if (pass == 0) {
      const int nf0 = (c == 3) ? 2 : 1;   // TOPO: c1->1, c2->1, c3->2
      unsigned k0 = key32[order[0]];       // essential creator = global argmin (stable)
      unsigned u0 = (k0 & 0x80000000u) ? (k0 & 0x7FFFFFFFu) : ~k0;
      float vmin = __uint_as_float(u0);
      if (nf0 == 1) {
        contrib = vmin * vmin + (float)sumsq;
      } else {
        if (cnt >= 1)
          contrib = vmin * vmin + (1.0f - maxp) * (1.0f - maxp)
                  + (float)(sumsq - (double)maxp * (double)maxp);
        else
          contrib = vmin * vmin + 1.0f;    // missing feature costs 1
      }
    } else {
      const int nf1 = (c == 2) ? 1 : 0;   // TOPO: c1->0, c2->1, c3->0
      if (nf1 == 0) {
        contrib = (float)sumsq;
      } else {
        contrib = (cnt >= 1)
          ? ((1.0f - maxp) * (1.0f - maxp) + (float)(sumsq - (double)maxp * (double)maxp))
          : 1.0f;                          // missing feature costs 1
      }
    }
    atomicAdd(out, contrib * 0.25f);       // / B, B = 4
  }
}

extern "C" void kernel_launch(void* const* d_in, const int* in_sizes, int n_in,
                              void* d_out, int out_size, void* d_ws, size_t ws_size,
                              hipStream_t stream) {
  const float* x = (const float*)d_in[0];
  float* out = (float*)d_out;
  ph_zero_kernel<<<1, 1, 0, stream>>>(out);
  ph_pass_kernel<<<24, NT, 0, stream>>>(x, out);
}

// Round 2
// 7001.287 us; speedup vs baseline: 1.1433x; 1.1433x over previous
//
#include <hip/hip_runtime.h>

#define NPIX 4096
#define NT 256
#define PPT (NPIX / NT)   // 16 pixels per thread

__global__ void ph_zero_kernel(float* out) { out[0] = 0.0f; }

__global__ __launch_bounds__(NT) void ph_pass_kernel(const float* __restrict__ x,
                                                     float* __restrict__ out) {
  __shared__ unsigned key32[NPIX];               // 16 KB: sortable key per pixel
  __shared__ unsigned long long sbuf[NPIX];      // 32 KB: sort buffer; later cand + UF
  __shared__ unsigned short label[NPIX];         // 8 KB: watershed basin labels
  __shared__ unsigned scan[NT];                  // 1 KB: block scan
  __shared__ unsigned s_mink;
  __shared__ int s_M;

  const int blk = blockIdx.x;            // 24 blocks: b(4) x c(3) x pass(2)
  const int b = blk / 6;
  const int rem = blk % 6;
  const int c = (rem >> 1) + 1;          // classes 1..3
  const int pass = rem & 1;              // 0 = sublevel 8-conn (H0), 1 = superlevel 4-conn (H1)
  const float* img = x + (size_t)(b * 4 + c) * NPIX;
  const int tid = threadIdx.x;
  const int ndirs = pass ? 4 : 8;
  const int drr[8] = {-1, 1, 0, 0, -1, -1, 1, 1};
  const int dcc[8] = { 0, 0,-1, 1, -1,  1, -1, 1};

  // --- monotone sortable keys; pass 1 negates (superlevel) ---
  for (int i = tid; i < NPIX; i += NT) {
    float f = img[i];
    if (pass) f = -f;
    unsigned u = __float_as_uint(f);
    unsigned k = (u & 0x80000000u) ? ~u : (u | 0x80000000u);
    key32[i] = k;
    sbuf[i] = ((unsigned long long)k << 32) | (unsigned)i;
  }
  __syncthreads();

  // --- bitonic sort ascending on (key, idx) ---
  for (int k = 2; k <= NPIX; k <<= 1) {
    for (int j = k >> 1; j > 0; j >>= 1) {
      for (int i = tid; i < NPIX; i += NT) {
        int ixj = i ^ j;
        if (ixj > i) {
          unsigned long long va = sbuf[i], vb = sbuf[ixj];
          bool up = ((i & k) == 0);
          if ((va > vb) == up) { sbuf[i] = vb; sbuf[ixj] = va; }
        }
      }
      __syncthreads();
    }
  }

  // --- watershed: ptr[i] = argmin-(key,idx) neighbor if lower, else i ---
  for (int i = tid; i < NPIX; i += NT) {
    unsigned long long me = ((unsigned long long)key32[i] << 32) | (unsigned)i;
    unsigned long long best = me;
    int bestnb = i;
    int r = i >> 6, cc = i & 63;
    for (int d = 0; d < ndirs; d++) {
      int rr = r + drr[d], c2 = cc + dcc[d];
      if ((unsigned)rr >= 64u || (unsigned)c2 >= 64u) continue;
      int nb = (rr << 6) | c2;
      unsigned long long pn = ((unsigned long long)key32[nb] << 32) | (unsigned)nb;
      if (pn < best) { best = pn; bestnb = nb; }
    }
    label[i] = (unsigned short)bestnb;
  }
  __syncthreads();
  // pointer jumping to basin roots (monotone -> race-safe); 2^12 covers any chain
  for (int round = 0; round < 12; round++) {
    for (int i = tid; i < NPIX; i += NT) {
      unsigned short l = label[i];
      label[i] = label[l];
    }
    __syncthreads();
  }

  // --- pull sorted entries (contiguous chunks) into registers ---
  unsigned long long ent[PPT];
  #pragma unroll
  for (int t = 0; t < PPT; t++) ent[t] = sbuf[tid * PPT + t];
  __syncthreads();

  // --- candidate flags: has a lower-rank neighbor in a different basin ---
  unsigned flags = 0;
  int cnt = 0;
  for (int t = 0; t < PPT; t++) {
    unsigned long long e = ent[t];
    int idx = (int)(e & 0xFFFFull);
    unsigned short mylab = label[idx];
    int r = idx >> 6, cc = idx & 63;
    bool f = false;
    for (int d = 0; d < ndirs; d++) {
      int rr = r + drr[d], c2 = cc + dcc[d];
      if ((unsigned)rr >= 64u || (unsigned)c2 >= 64u) continue;
      int nb = (rr << 6) | c2;
      unsigned long long pn = ((unsigned long long)key32[nb] << 32) | (unsigned)nb;
      if (pn < e && label[nb] != mylab) { f = true; break; }
    }
    if (f) { flags |= 1u << t; cnt++; }
  }
  scan[tid] = (unsigned)cnt;
  __syncthreads();
  for (int off = 1; off < NT; off <<= 1) {
    unsigned v = scan[tid];
    unsigned add = (tid >= off) ? scan[tid - off] : 0u;
    __syncthreads();
    scan[tid] = v + add;
    __syncthreads();
  }
  int base = (int)scan[tid] - cnt;
  if (tid == NT - 1) s_M = (int)scan[NT - 1];
  if (tid == 0) s_mink = (unsigned)(ent[0] >> 32);   // global min key (essential birth)

  // --- alias sbuf: cand list + basin union-find parents ---
  unsigned short* cand = (unsigned short*)sbuf;          // [0, 8K)
  unsigned short* uf   = ((unsigned short*)sbuf) + NPIX; // [8K, 16K)
  {
    int pos = base;
    for (int t = 0; t < PPT; t++)
      if (flags & (1u << t)) cand[pos++] = (unsigned short)(ent[t] & 0xFFFFull);
  }
  for (int i = tid; i < NPIX; i += NT) uf[i] = (unsigned short)i;
  __syncthreads();

  // --- serial merge phase over candidates only (thread 0) ---
  if (tid == 0) {
    double sumsq = 0.0;
    float maxp = 0.0f;
    int pcnt = 0;
    const int M = s_M;
    for (int j = 0; j < M; j++) {
      const int idx = cand[j];
      const unsigned k = key32[idx];
      const unsigned long long me = ((unsigned long long)k << 32) | (unsigned)idx;
      const int r = idx >> 6, cc = idx & 63;
      // distinct lower-neighbor basin labels
      int labs[8]; int nl = 0;
      for (int d = 0; d < ndirs; d++) {
        int rr = r + drr[d], c2 = cc + dcc[d];
        if ((unsigned)rr >= 64u || (unsigned)c2 >= 64u) continue;
        int nb = (rr << 6) | c2;
        unsigned long long pn = ((unsigned long long)key32[nb] << 32) | (unsigned)nb;
        if (pn >= me) continue;
        int lb = label[nb];
        bool dup = false;
        for (int q = 0; q < nl; q++) if (labs[q] == lb) { dup = true; break; }
        if (!dup) labs[nl++] = lb;
      }
      // find roots (path halving), dedupe
      int roots[8]; int nr = 0;
      for (int q = 0; q < nl; q++) {
        int a = labs[q];
        while (true) {
          int p = uf[a];
          if (p == a) break;
          int gp = uf[p];
          uf[a] = (unsigned short)gp;
          a = gp;
        }
        bool dup = false;
        for (int t2 = 0; t2 < nr; t2++) if (roots[t2] == a) { dup = true; break; }
        if (!dup) roots[nr++] = a;
      }
      if (nr < 2) continue;
      // elder = root with min (key, idx); creator of a root is the root itself
      int elder = roots[0];
      unsigned long long eb = ((unsigned long long)key32[elder] << 32) | (unsigned)elder;
      for (int t2 = 1; t2 < nr; t2++) {
        unsigned long long pb =
            ((unsigned long long)key32[roots[t2]] << 32) | (unsigned)roots[t2];
        if (pb < eb) { eb = pb; elder = roots[t2]; }
      }
      for (int t2 = 0; t2 < nr; t2++) {
        int rt = roots[t2];
        if (rt == elder) continue;
        unsigned ky = key32[rt];
        if (k > ky) {   // strictly positive persistence (monotone key)
          unsigned ui = (k  & 0x80000000u) ? (k  & 0x7FFFFFFFu) : ~k;
          unsigned uy = (ky & 0x80000000u) ? (ky & 0x7FFFFFFFu) : ~ky;
          float pers = __uint_as_float(ui) - __uint_as_float(uy);
          sumsq += (double)pers * (double)pers;
          maxp = fmaxf(maxp, pers);
          pcnt++;
        }
        uf[rt] = (unsigned short)elder;
      }
    }

    // --- per-(b,c,pass) loss contribution ---
    float contrib;
    if (pass == 0) {
      const int nf0 = (c == 3) ? 2 : 1;   // TOPO H0: c1->1, c2->1, c3->2
      unsigned k0 = s_mink;
      unsigned u0 = (k0 & 0x80000000u) ? (k0 & 0x7FFFFFFFu) : ~k0;
      float vmin = __uint_as_float(u0);
      if (nf0 == 1) {
        contrib = vmin * vmin + (float)sumsq;
      } else {
        if (pcnt >= 1)
          contrib = vmin * vmin + (1.0f - maxp) * (1.0f - maxp)
                  + (float)(sumsq - (double)maxp * (double)maxp);
        else
          contrib = vmin * vmin + 1.0f;
      }
    } else {
      const int nf1 = (c == 2) ? 1 : 0;   // TOPO H1: c1->0, c2->1, c3->0
      if (nf1 == 0) {
        contrib = (float)sumsq;
      } else {
        contrib = (pcnt >= 1)
          ? ((1.0f - maxp) * (1.0f - maxp) + (float)(sumsq - (double)maxp * (double)maxp))
          : 1.0f;
      }
    }
    atomicAdd(out, contrib * 0.25f);   // / B, B = 4
  }
}

extern "C" void kernel_launch(void* const* d_in, const int* in_sizes, int n_in,
                              void* d_out, int out_size, void* d_ws, size_t ws_size,
                              hipStream_t stream) {
  const float* x = (const float*)d_in[0];
  float* out = (float*)d_out;
  ph_zero_kernel<<<1, 1, 0, stream>>>(out);
  ph_pass_kernel<<<24, NT, 0, stream>>>(x, out);
}

// Round 3
// 1134.166 us; speedup vs baseline: 7.0576x; 6.1731x over previous
//
#include <hip/hip_runtime.h>

#define NPIX 4096
#define NT 256
#define PPT (NPIX / NT)   // 16 hash slots per thread
#define EMPTY 0xFFFFFFFFu

__global__ void ph_zero_kernel(float* out) { out[0] = 0.0f; }

__device__ __forceinline__ float kval(unsigned k) {
  unsigned u = (k & 0x80000000u) ? (k & 0x7FFFFFFFu) : ~k;
  return __uint_as_float(u);
}

__global__ __launch_bounds__(NT) void ph_pass_kernel(const float* __restrict__ x,
                                                     float* __restrict__ out) {
  __shared__ unsigned key32[NPIX];               // 16 KB: sortable key per pixel
  __shared__ unsigned long long sbuf[NPIX];      // 32 KB: hash table, then edge sort
  __shared__ unsigned short label[NPIX];         // 8 KB: basin labels -> UF parents
  __shared__ unsigned scan[NT];                  // 1 KB
  __shared__ unsigned s_mink;
  __shared__ int s_M;

  unsigned* hkey = (unsigned*)sbuf;              // [0, 16K): pair keys
  unsigned* hval = hkey + NPIX;                  // [16K, 32K): min edge weight key

  const int blk = blockIdx.x;            // 24 blocks: b(4) x c(3) x pass(2)
  const int b = blk / 6;
  const int rem = blk % 6;
  const int c = (rem >> 1) + 1;          // classes 1..3
  const int pass = rem & 1;              // 0 = sublevel 8-conn (H0), 1 = superlevel 4-conn (H1)
  const float* img = x + (size_t)(b * 4 + c) * NPIX;
  const int tid = threadIdx.x;
  const int ndirs = pass ? 4 : 8;
  const int drr[8] = {-1, 1, 0, 0, -1, -1, 1, 1};
  const int dcc[8] = { 0, 0,-1, 1, -1,  1, -1, 1};

  // --- keys (monotone float->u32; pass 1 negates), hash init, global min ---
  if (tid == 0) s_mink = EMPTY;
  unsigned lmin = EMPTY;
  for (int i = tid; i < NPIX; i += NT) {
    float f = img[i];
    if (pass) f = -f;
    unsigned u = __float_as_uint(f);
    unsigned k = (u & 0x80000000u) ? ~u : (u | 0x80000000u);
    key32[i] = k;
    hkey[i] = EMPTY;
    hval[i] = EMPTY;
    lmin = min(lmin, k);
  }
  __syncthreads();
  atomicMin(&s_mink, lmin);

  // --- watershed: pointer to argmin-(key,idx) neighbor, then pointer jumping ---
  for (int i = tid; i < NPIX; i += NT) {
    unsigned long long best = ((unsigned long long)key32[i] << 32) | (unsigned)i;
    int bestnb = i;
    int r = i >> 6, cc = i & 63;
    for (int d = 0; d < ndirs; d++) {
      int rr = r + drr[d], c2 = cc + dcc[d];
      if ((unsigned)rr >= 64u || (unsigned)c2 >= 64u) continue;
      int nb = (rr << 6) | c2;
      unsigned long long pn = ((unsigned long long)key32[nb] << 32) | (unsigned)nb;
      if (pn < best) { best = pn; bestnb = nb; }
    }
    label[i] = (unsigned short)bestnb;
  }
  __syncthreads();
  for (int round = 0; round < 12; round++) {     // 2^12 covers any chain
    for (int i = tid; i < NPIX; i += NT) {
      unsigned short l = label[i];
      label[i] = label[l];                       // monotone jumps -> race-safe
    }
    __syncthreads();
  }

  // --- inter-basin edges, deduped to min weight per basin pair via LDS hash ---
  // positive directions only: each undirected pixel edge enumerated once
  const int pdr[4] = {1, 0, 1,  1};
  const int pdc[4] = {0, 1, 1, -1};
  const int npd = pass ? 2 : 4;
  for (int i = tid; i < NPIX; i += NT) {
    int r = i >> 6, cc = i & 63;
    unsigned la = label[i];
    unsigned ki = key32[i];
    for (int d = 0; d < npd; d++) {
      int rr = r + pdr[d], c2 = cc + pdc[d];
      if ((unsigned)rr >= 64u || (unsigned)c2 >= 64u) continue;
      int nb = (rr << 6) | c2;
      unsigned lb = label[nb];
      if (lb == la) continue;
      unsigned wkey = max(ki, key32[nb]);        // edge weight = max endpoint value key
      unsigned pk = la < lb ? ((la << 12) | lb) : ((lb << 12) | la);  // 24-bit pair id
      unsigned h = (pk * 2654435761u) >> 20;     // 12-bit hash, linear probe
      while (true) {
        unsigned old = atomicCAS(&hkey[h], EMPTY, pk);
        if (old == EMPTY || old == pk) { atomicMin(&hval[h], wkey); break; }
        h = (h + 1) & (NPIX - 1);
      }
    }
  }
  __syncthreads();

  // --- compact hash entries into sort items (wkey<<32 | pairkey) ---
  unsigned long long item[PPT];
  int cnt = 0;
  for (int q = 0; q < PPT; q++) {
    int s = tid * PPT + q;
    unsigned pk = hkey[s];
    if (pk != EMPTY) item[cnt++] = (((unsigned long long)hval[s]) << 32) | pk;
  }
  scan[tid] = (unsigned)cnt;
  __syncthreads();
  for (int off = 1; off < NT; off <<= 1) {
    unsigned v = scan[tid];
    unsigned add = (tid >= off) ? scan[tid - off] : 0u;
    __syncthreads();
    scan[tid] = v + add;
    __syncthreads();
  }
  int base = (int)scan[tid] - cnt;
  if (tid == NT - 1) s_M = (int)scan[NT - 1];
  __syncthreads();
  for (int q = 0; q < cnt; q++) sbuf[base + q] = item[q];
  const int M = s_M;
  for (int i = M + tid; i < NPIX; i += NT) sbuf[i] = ~0ull;   // pad sorts to end
  for (int i = tid; i < NPIX; i += NT) label[i] = (unsigned short)i;  // UF parents
  __syncthreads();

  // --- bitonic sort edges ascending by weight key ---
  for (int k = 2; k <= NPIX; k <<= 1) {
    for (int j = k >> 1; j > 0; j >>= 1) {
      for (int i = tid; i < NPIX; i += NT) {
        int ixj = i ^ j;
        if (ixj > i) {
          unsigned long long va = sbuf[i], vb = sbuf[ixj];
          bool up = ((i & k) == 0);
          if ((va > vb) == up) { sbuf[i] = vb; sbuf[ixj] = va; }
        }
      }
      __syncthreads();
    }
  }

  // --- serial Kruskal over deduped basin edges (thread 0) ---
  if (tid == 0) {
    double sumsq = 0.0;
    float maxp = 0.0f;
    int pcnt = 0;
    for (int j = 0; j < M; j++) {
      unsigned long long e = sbuf[j];
      unsigned wk = (unsigned)(e >> 32);
      unsigned pk = (unsigned)(e & 0xFFFFFFu);
      int a = (int)(pk >> 12), bn = (int)(pk & 0xFFFu);
      int ra = a;
      while (true) { int p = label[ra]; if (p == ra) break;
                     int gp = label[p]; label[ra] = (unsigned short)gp; ra = gp; }
      int rb = bn;
      while (true) { int p = label[rb]; if (p == rb) break;
                     int gp = label[p]; label[rb] = (unsigned short)gp; rb = gp; }
      if (ra == rb) continue;
      unsigned ka = key32[ra], kb = key32[rb];   // root = basin min pixel = creator
      bool a_elder = (ka < kb) || (ka == kb && ra < rb);
      int elder = a_elder ? ra : rb;
      int young = a_elder ? rb : ra;
      unsigned ky = a_elder ? kb : ka;
      if (wk > ky) {                             // strictly positive persistence
        float pers = kval(wk) - kval(ky);
        sumsq += (double)pers * (double)pers;
        maxp = fmaxf(maxp, pers);
        pcnt++;
      }
      label[young] = (unsigned short)elder;
    }

    // --- per-(b,c,pass) loss contribution ---
    float contrib;
    if (pass == 0) {
      const int nf0 = (c == 3) ? 2 : 1;          // TOPO H0: c1->1, c2->1, c3->2
      float vmin = kval(s_mink);                 // essential birth = global min
      if (nf0 == 1) {
        contrib = vmin * vmin + (float)sumsq;
      } else if (pcnt >= 1) {
        contrib = vmin * vmin + (1.0f - maxp) * (1.0f - maxp)
                + (float)(sumsq - (double)maxp * (double)maxp);
      } else {
        contrib = vmin * vmin + 1.0f;
      }
    } else {
      const int nf1 = (c == 2) ? 1 : 0;          // TOPO H1: c1->0, c2->1, c3->0
      if (nf1 == 0) contrib = (float)sumsq;
      else contrib = (pcnt >= 1)
        ? ((1.0f - maxp) * (1.0f - maxp) + (float)(sumsq - (double)maxp * (double)maxp))
        : 1.0f;
    }
    atomicAdd(out, contrib * 0.25f);             // / B, B = 4
  }
}

extern "C" void kernel_launch(void* const* d_in, const int* in_sizes, int n_in,
                              void* d_out, int out_size, void* d_ws, size_t ws_size,
                              hipStream_t stream) {
  const float* x = (const float*)d_in[0];
  float* out = (float*)d_out;
  ph_zero_kernel<<<1, 1, 0, stream>>>(out);
  ph_pass_kernel<<<24, NT, 0, stream>>>(x, out);
}

// Round 5
// 784.653 us; speedup vs baseline: 10.2013x; 1.4454x over previous
//
#include <hip/hip_runtime.h>

#define NPIX 4096
#define NT 256
#define PPT (NPIX / NT)   // 16 per thread
#define EMPTY 0xFFFFFFFFu
#define CHUNK 128

__global__ void ph_zero_kernel(float* out) { out[0] = 0.0f; }

__device__ __forceinline__ float kval(unsigned k) {
  unsigned u = (k & 0x80000000u) ? (k & 0x7FFFFFFFu) : ~k;
  return __uint_as_float(u);
}

__global__ __launch_bounds__(NT) void ph_pass_kernel(const float* __restrict__ x,
                                                     float* __restrict__ out) {
  // One 64 KB pool, phase-aliased:
  //  [0,32K)  : hash (hkey 16K | hval 16K)  ->  sorted edge list (u64[4096])
  //  [32K,48K): key32 u32[4096]             ->  (clobbered by node records in ph.6)
  //  [48K,56K): label u16[4096]             ->  (clobbered by node records in ph.6)
  //  [32K,64K): node u64[4096] = creatorKey<<32 | parent   (Kruskal phase)
  __shared__ unsigned long long pool[2 * NPIX];

  unsigned long long* sbuf = pool;
  unsigned* hkey = (unsigned*)pool;
  unsigned* hval = hkey + NPIX;
  unsigned* scanA = (unsigned*)pool;                       // scratch (pre-hash / post-read)
  unsigned* key32 = (unsigned*)(pool + NPIX);
  unsigned short* label = (unsigned short*)(pool + NPIX + NPIX / 2);
  unsigned long long* node = pool + NPIX;

  const int blk = blockIdx.x;            // 24 blocks: b(4) x c(3) x pass(2)
  const int b = blk / 6;
  const int rem = blk % 6;
  const int c = (rem >> 1) + 1;          // classes 1..3
  const int pass = rem & 1;              // 0 = sublevel 8-conn (H0), 1 = superlevel 4-conn (H1)
  const float* img = x + (size_t)(b * 4 + c) * NPIX;
  const int tid = threadIdx.x;
  const int ndirs = pass ? 4 : 8;
  const int drr[8] = {-1, 1, 0, 0, -1, -1, 1, 1};
  const int dcc[8] = { 0, 0,-1, 1, -1,  1, -1, 1};

  // --- phase 1: monotone keys (pass 1 negates); per-thread min ---
  unsigned lmin = EMPTY;
  for (int i = tid; i < NPIX; i += NT) {
    float f = img[i];
    if (pass) f = -f;
    unsigned u = __float_as_uint(f);
    unsigned k = (u & 0x80000000u) ? ~u : (u | 0x80000000u);
    key32[i] = k;
    lmin = min(lmin, k);
  }
  __syncthreads();

  // --- phase 2: watershed pointers + pointer jumping ---
  for (int i = tid; i < NPIX; i += NT) {
    unsigned long long best = ((unsigned long long)key32[i] << 32) | (unsigned)i;
    int bestnb = i;
    int r = i >> 6, cc = i & 63;
    for (int d = 0; d < ndirs; d++) {
      int rr = r + drr[d], c2 = cc + dcc[d];
      if ((unsigned)rr >= 64u || (unsigned)c2 >= 64u) continue;
      int nb = (rr << 6) | c2;
      unsigned long long pn = ((unsigned long long)key32[nb] << 32) | (unsigned)nb;
      if (pn < best) { best = pn; bestnb = nb; }
    }
    label[i] = (unsigned short)bestnb;
  }
  __syncthreads();
  for (int round = 0; round < 12; round++) {
    for (int i = tid; i < NPIX; i += NT) {
      unsigned short l = label[i];
      label[i] = label[l];               // monotone -> race-safe
    }
    __syncthreads();
  }

  // --- phase 3: reduce global min key via scratch (pool[0..32K) still free) ---
  scanA[tid] = lmin;
  __syncthreads();
  for (int off = NT / 2; off > 0; off >>= 1) {
    if (tid < off) scanA[tid] = min(scanA[tid], scanA[tid + off]);
    __syncthreads();
  }
  const unsigned vmink = scanA[0];       // register copy
  __syncthreads();

  // --- phase 4: hash init — ONLY pool[0..NPIX) (32 KB); key32/label live above! ---
  for (int i = tid; i < NPIX; i += NT) pool[i] = ~0ull;    // hkey=hval=EMPTY
  __syncthreads();

  // --- phase 5: inter-basin edges deduped to min weight per basin pair ---
  const int pdr[4] = {1, 0, 1,  1};
  const int pdc[4] = {0, 1, 1, -1};
  const int npd = pass ? 2 : 4;
  for (int i = tid; i < NPIX; i += NT) {
    int r = i >> 6, cc = i & 63;
    unsigned la = label[i];
    unsigned ki = key32[i];
    for (int d = 0; d < npd; d++) {
      int rr = r + pdr[d], c2 = cc + pdc[d];
      if ((unsigned)rr >= 64u || (unsigned)c2 >= 64u) continue;
      int nb = (rr << 6) | c2;
      unsigned lb = label[nb];
      if (lb == la) continue;
      unsigned wkey = max(ki, key32[nb]);                  // weight = max endpoint key
      unsigned pk = la < lb ? ((la << 12) | lb) : ((lb << 12) | la);
      unsigned h = (pk * 2654435761u) >> 20;
      while (true) {
        unsigned old = atomicCAS(&hkey[h], EMPTY, pk);
        if (old == EMPTY || old == pk) { atomicMin(&hval[h], wkey); break; }
        h = (h + 1) & (NPIX - 1);
      }
    }
  }
  __syncthreads();

  // --- phase 6: stage hash + keys into regs; scan; write edges + node records ---
  unsigned long long item[PPT];
  unsigned mykeys[PPT];
  int cnt = 0;
  for (int q = 0; q < PPT; q++) {
    int s = tid * PPT + q;
    unsigned pk = hkey[s];
    if (pk != EMPTY) item[cnt++] = (((unsigned long long)hval[s]) << 32) | pk;
  }
  #pragma unroll
  for (int t = 0; t < PPT; t++) mykeys[t] = key32[tid + t * NT];
  __syncthreads();                        // all reads of pool[0..56K) done
  scanA[tid] = (unsigned)cnt;
  __syncthreads();
  for (int off = 1; off < NT; off <<= 1) {
    unsigned v = scanA[tid];
    unsigned add = (tid >= off) ? scanA[tid - off] : 0u;
    __syncthreads();
    scanA[tid] = v + add;
    __syncthreads();
  }
  const int M = (int)scanA[NT - 1];
  const int base = (int)scanA[tid] - cnt;
  __syncthreads();                        // scan consumed; safe to clobber
  for (int q = 0; q < cnt; q++) sbuf[base + q] = item[q];
  #pragma unroll
  for (int t = 0; t < PPT; t++) {
    int i = tid + t * NT;
    node[i] = (((unsigned long long)mykeys[t]) << 32) | (unsigned)i;  // singleton
  }
  for (int i = M + tid; i < NPIX; i += NT) sbuf[i] = ~0ull;           // sort pad
  __syncthreads();

  // --- phase 7: bitonic sort edges ascending by weight key ---
  for (int k = 2; k <= NPIX; k <<= 1) {
    for (int j = k >> 1; j > 0; j >>= 1) {
      for (int i = tid; i < NPIX; i += NT) {
        int ixj = i ^ j;
        if (ixj > i) {
          unsigned long long va = sbuf[i], vb = sbuf[ixj];
          bool up = ((i & k) == 0);
          if ((va > vb) == up) { sbuf[i] = vb; sbuf[ixj] = va; }
        }
      }
      __syncthreads();
    }
  }

  // --- phase 8: chunked serial Kruskal (thread 0) + parallel flatten ---
  double sumsq = 0.0;
  float maxp = 0.0f;
  int pcnt = 0;
  for (int cs = 0; cs < M; cs += CHUNK) {
    const int ce = min(M, cs + CHUNK);
    if (tid == 0) {
      unsigned long long e = sbuf[cs];
      for (int j = cs; j < ce; j++) {
        unsigned long long enext = (j + 1 < ce) ? sbuf[j + 1] : 0ull;  // prefetch
        unsigned wk = (unsigned)(e >> 32);
        unsigned pk = (unsigned)(e & 0xFFFFFFu);
        unsigned xa = pk >> 12, xb = pk & 0xFFFu;
        unsigned long long ra = node[xa];
        unsigned long long rb = node[xb];     // both loads in flight together
        while ((unsigned)ra != xa) { xa = (unsigned)ra; ra = node[xa]; }
        while ((unsigned)rb != xb) { xb = (unsigned)rb; rb = node[xb]; }
        e = enext;
        if (xa == xb) continue;
        // record = (creatorKey<<32)|idx: u64 compare = (key, idx) elder rule
        unsigned long long elder = ra < rb ? ra : rb;
        unsigned long long young = ra < rb ? rb : ra;
        unsigned ky = (unsigned)(young >> 32);
        if (wk > ky) {                        // strictly positive persistence
          float pers = kval(wk) - kval(ky);
          sumsq += (double)pers * (double)pers;
          maxp = fmaxf(maxp, pers);
          pcnt++;
        }
        node[(unsigned)young] = (young & 0xFFFFFFFF00000000ull) | (unsigned)elder;
      }
    }
    __syncthreads();
    // parallel flatten to depth 1 (key half never changes; ptrs monotone to root)
    for (int i = tid; i < NPIX; i += NT) {
      unsigned long long rec = node[i];
      unsigned px = (unsigned)rec;
      if (px == (unsigned)i) continue;
      unsigned long long r2 = node[px];
      while ((unsigned)r2 != px) { px = (unsigned)r2; r2 = node[px]; }
      node[i] = (rec & 0xFFFFFFFF00000000ull) | px;
    }
    __syncthreads();
  }

  // --- phase 9: loss contribution ---
  if (tid == 0) {
    float contrib;
    if (pass == 0) {
      const int nf0 = (c == 3) ? 2 : 1;      // TOPO H0: c1->1, c2->1, c3->2
      float vmin = kval(vmink);              // essential birth = global min
      if (nf0 == 1) {
        contrib = vmin * vmin + (float)sumsq;
      } else if (pcnt >= 1) {
        contrib = vmin * vmin + (1.0f - maxp) * (1.0f - maxp)
                + (float)(sumsq - (double)maxp * (double)maxp);
      } else {
        contrib = vmin * vmin + 1.0f;
      }
    } else {
      const int nf1 = (c == 2) ? 1 : 0;      // TOPO H1: c1->0, c2->1, c3->0
      if (nf1 == 0) contrib = (float)sumsq;
      else contrib = (pcnt >= 1)
        ? ((1.0f - maxp) * (1.0f - maxp) + (float)(sumsq - (double)maxp * (double)maxp))
        : 1.0f;
    }
    atomicAdd(out, contrib * 0.25f);         // / B, B = 4
  }
}

extern "C" void kernel_launch(void* const* d_in, const int* in_sizes, int n_in,
                              void* d_out, int out_size, void* d_ws, size_t ws_size,
                              hipStream_t stream) {
  const float* x = (const float*)d_in[0];
  float* out = (float*)d_out;
  ph_zero_kernel<<<1, 1, 0, stream>>>(out);
  ph_pass_kernel<<<24, NT, 0, stream>>>(x, out);
}

// Round 6
// 660.823 us; speedup vs baseline: 12.1129x; 1.1874x over previous
//
#include <hip/hip_runtime.h>

#define NPIX 4096
#define NT 1024
#define PPT (NPIX / NT)   // 4 per thread
#define EMPTY 0xFFFFFFFFu
#define CHUNK 128

__global__ void ph_zero_kernel(float* out) { out[0] = 0.0f; }

__device__ __forceinline__ float kval(unsigned k) {
  unsigned u = (k & 0x80000000u) ? (k & 0x7FFFFFFFu) : ~k;
  return __uint_as_float(u);
}

__global__ __launch_bounds__(NT) void ph_pass_kernel(const float* __restrict__ x,
                                                     float* __restrict__ out) {
  // One 64 KB pool, phase-aliased:
  //  [0,32K)  : hash (hkey 16K | hval 16K)  ->  sorted edge list (u64)
  //  [32K,48K): key32 u32[4096]             ->  clobbered by node records (ph.6)
  //  [48K,56K): label u16[4096]             ->  clobbered by node records (ph.6)
  //  [32K,64K): node u64[4096] = creatorKey<<32 | parent   (Kruskal phase)
  __shared__ unsigned long long pool[2 * NPIX];
  __shared__ unsigned wred[16];          // per-wave scan/reduce staging

  unsigned long long* sbuf = pool;
  unsigned* hkey = (unsigned*)pool;
  unsigned* hval = hkey + NPIX;
  unsigned* key32 = (unsigned*)(pool + NPIX);
  unsigned short* label = (unsigned short*)(pool + NPIX + NPIX / 2);
  unsigned long long* node = pool + NPIX;

  const int blk = blockIdx.x;            // 24 blocks: b(4) x c(3) x pass(2)
  const int b = blk / 6;
  const int rem = blk % 6;
  const int c = (rem >> 1) + 1;          // classes 1..3
  const int pass = rem & 1;              // 0 = sublevel 8-conn (H0), 1 = superlevel 4-conn (H1)
  const float* img = x + (size_t)(b * 4 + c) * NPIX;
  const int tid = threadIdx.x;
  const int lane = tid & 63, wid = tid >> 6;
  const int ndirs = pass ? 4 : 8;
  const int drr[8] = {-1, 1, 0, 0, -1, -1, 1, 1};
  const int dcc[8] = { 0, 0,-1, 1, -1,  1, -1, 1};

  // --- phase 1: monotone keys (pass 1 negates); per-thread min ---
  unsigned lmin = EMPTY;
  for (int i = tid; i < NPIX; i += NT) {
    float f = img[i];
    if (pass) f = -f;
    unsigned u = __float_as_uint(f);
    unsigned k = (u & 0x80000000u) ? ~u : (u | 0x80000000u);
    key32[i] = k;
    lmin = min(lmin, k);
  }
  // wave-level min, then cross-wave via wred
  for (int off = 32; off > 0; off >>= 1)
    lmin = min(lmin, (unsigned)__shfl_xor((int)lmin, off));
  if (lane == 0) wred[wid] = lmin;
  __syncthreads();                       // also covers key32 writes
  unsigned vmink = wred[0];
  #pragma unroll
  for (int w = 1; w < 16; w++) vmink = min(vmink, wred[w]);

  // --- phase 2: watershed pointers + pointer jumping ---
  for (int i = tid; i < NPIX; i += NT) {
    unsigned long long best = ((unsigned long long)key32[i] << 32) | (unsigned)i;
    int bestnb = i;
    int r = i >> 6, cc = i & 63;
    for (int d = 0; d < ndirs; d++) {
      int rr = r + drr[d], c2 = cc + dcc[d];
      if ((unsigned)rr >= 64u || (unsigned)c2 >= 64u) continue;
      int nb = (rr << 6) | c2;
      unsigned long long pn = ((unsigned long long)key32[nb] << 32) | (unsigned)nb;
      if (pn < best) { best = pn; bestnb = nb; }
    }
    label[i] = (unsigned short)bestnb;
  }
  __syncthreads();
  for (int round = 0; round < 12; round++) {
    for (int i = tid; i < NPIX; i += NT) {
      unsigned short l = label[i];
      label[i] = label[l];               // monotone -> race-safe
    }
    __syncthreads();
  }

  // --- phase 3: hash init — ONLY pool[0..NPIX) (32 KB); key32/label live above ---
  for (int i = tid; i < NPIX; i += NT) pool[i] = ~0ull;    // hkey=hval=EMPTY
  __syncthreads();

  // --- phase 4: inter-basin edges deduped to min weight per basin pair ---
  const int pdr[4] = {1, 0, 1,  1};
  const int pdc[4] = {0, 1, 1, -1};
  const int npd = pass ? 2 : 4;
  for (int i = tid; i < NPIX; i += NT) {
    int r = i >> 6, cc = i & 63;
    unsigned la = label[i];
    unsigned ki = key32[i];
    for (int d = 0; d < npd; d++) {
      int rr = r + pdr[d], c2 = cc + pdc[d];
      if ((unsigned)rr >= 64u || (unsigned)c2 >= 64u) continue;
      int nb = (rr << 6) | c2;
      unsigned lb = label[nb];
      if (lb == la) continue;
      unsigned wkey = max(ki, key32[nb]);                  // weight = max endpoint key
      unsigned pk = la < lb ? ((la << 12) | lb) : ((lb << 12) | la);
      unsigned h = (pk * 2654435761u) >> 20;
      while (true) {
        unsigned old = atomicCAS(&hkey[h], EMPTY, pk);
        if (old == EMPTY || old == pk) { atomicMin(&hval[h], wkey); break; }
        h = (h + 1) & (NPIX - 1);
      }
    }
  }
  __syncthreads();

  // --- phase 5: stage hash + keys into regs; shfl-scan; write edges + nodes ---
  unsigned long long item[PPT];
  unsigned mykeys[PPT];
  int cnt = 0;
  #pragma unroll
  for (int q = 0; q < PPT; q++) {
    int s = tid * PPT + q;
    unsigned pk = hkey[s];
    if (pk != EMPTY) item[cnt++] = (((unsigned long long)hval[s]) << 32) | pk;
  }
  #pragma unroll
  for (int t = 0; t < PPT; t++) mykeys[t] = key32[tid + t * NT];
  __syncthreads();                       // all reads of pool[0..56K) done
  // intra-wave inclusive scan of cnt
  unsigned inc = (unsigned)cnt;
  for (int off = 1; off < 64; off <<= 1) {
    unsigned nvl = (unsigned)__shfl_up((int)inc, off);
    if (lane >= off) inc += nvl;
  }
  if (lane == 63) wred[wid] = inc;
  __syncthreads();
  if (tid == 0) {
    unsigned acc = 0;
    #pragma unroll
    for (int w = 0; w < 16; w++) { unsigned t2 = wred[w]; wred[w] = acc; acc += t2; }
    wred[15] = acc - (acc - wred[15]);   // keep exclusive bases; total via recompute below
  }
  __syncthreads();
  // total M = exclusive base of wave15 + wave15's inclusive last -> recompute:
  // simpler: every thread computes M from wred[15] + wave15 total via shfl broadcast
  // (wave15's inclusive total was overwritten; recover by summing cnt across wave15)
  // -> instead: recompute wave totals locally
  unsigned wbase = wred[wid];
  int base = (int)(wbase + inc - (unsigned)cnt);
  // block total: reduce cnt across all threads (cheap shfl + wred reuse)
  __syncthreads();
  unsigned tot = (unsigned)cnt;
  for (int off = 32; off > 0; off >>= 1) tot += (unsigned)__shfl_xor((int)tot, off);
  if (lane == 0) wred[wid] = tot;
  __syncthreads();
  unsigned Mu = 0;
  #pragma unroll
  for (int w = 0; w < 16; w++) Mu += wred[w];
  const int M = (int)Mu;
  __syncthreads();                       // wred consumed; pool writable
  for (int q = 0; q < cnt; q++) sbuf[base + q] = item[q];
  #pragma unroll
  for (int t = 0; t < PPT; t++) {
    int i = tid + t * NT;
    node[i] = (((unsigned long long)mykeys[t]) << 32) | (unsigned)i;  // singleton
  }
  // adaptive sort size: next pow2 >= M (min 256)
  int S = 256;
  while (S < M) S <<= 1;
  for (int i = M + tid; i < S; i += NT) sbuf[i] = ~0ull;   // sort pad
  __syncthreads();

  // --- phase 6: bitonic sort S edges ascending by weight key ---
  for (int k = 2; k <= S; k <<= 1) {
    for (int j = k >> 1; j > 0; j >>= 1) {
      for (int i = tid; i < S; i += NT) {
        int ixj = i ^ j;
        if (ixj > i) {
          unsigned long long va = sbuf[i], vb = sbuf[ixj];
          bool up = ((i & k) == 0);
          if ((va > vb) == up) { sbuf[i] = vb; sbuf[ixj] = va; }
        }
      }
      __syncthreads();
    }
  }

  // --- phase 7: chunked serial Kruskal (thread 0) + parallel flatten ---
  double sumsq = 0.0;
  float maxp = 0.0f;
  int pcnt = 0;
  for (int cs = 0; cs < M; cs += CHUNK) {
    const int ce = min(M, cs + CHUNK);
    if (tid == 0) {
      unsigned long long e = sbuf[cs];
      for (int j = cs; j < ce; j++) {
        unsigned long long enext = (j + 1 < ce) ? sbuf[j + 1] : 0ull;  // prefetch
        unsigned wk = (unsigned)(e >> 32);
        unsigned pk = (unsigned)(e & 0xFFFFFFu);
        unsigned xa = pk >> 12, xb = pk & 0xFFFu;
        unsigned long long ra = node[xa];
        unsigned long long rb = node[xb];     // both loads in flight together
        while ((unsigned)ra != xa) { xa = (unsigned)ra; ra = node[xa]; }
        while ((unsigned)rb != xb) { xb = (unsigned)rb; rb = node[xb]; }
        e = enext;
        if (xa == xb) continue;
        // record = (creatorKey<<32)|idx: u64 compare = (key, idx) elder rule
        unsigned long long elder = ra < rb ? ra : rb;
        unsigned long long young = ra < rb ? rb : ra;
        unsigned ky = (unsigned)(young >> 32);
        if (wk > ky) {                        // strictly positive persistence
          float pers = kval(wk) - kval(ky);
          sumsq += (double)pers * (double)pers;
          maxp = fmaxf(maxp, pers);
          pcnt++;
        }
        node[(unsigned)young] = (young & 0xFFFFFFFF00000000ull) | (unsigned)elder;
      }
    }
    __syncthreads();
    // parallel flatten to depth 1 (key half never changes; ptrs monotone to root)
    for (int i = tid; i < NPIX; i += NT) {
      unsigned long long rec = node[i];
      unsigned px = (unsigned)rec;
      if (px == (unsigned)i) continue;
      unsigned long long r2 = node[px];
      while ((unsigned)r2 != px) { px = (unsigned)r2; r2 = node[px]; }
      node[i] = (rec & 0xFFFFFFFF00000000ull) | px;
    }
    __syncthreads();
  }

  // --- phase 8: loss contribution ---
  if (tid == 0) {
    float contrib;
    if (pass == 0) {
      const int nf0 = (c == 3) ? 2 : 1;      // TOPO H0: c1->1, c2->1, c3->2
      float vmin = kval(vmink);              // essential birth = global min
      if (nf0 == 1) {
        contrib = vmin * vmin + (float)sumsq;
      } else if (pcnt >= 1) {
        contrib = vmin * vmin + (1.0f - maxp) * (1.0f - maxp)
                + (float)(sumsq - (double)maxp * (double)maxp);
      } else {
        contrib = vmin * vmin + 1.0f;
      }
    } else {
      const int nf1 = (c == 2) ? 1 : 0;      // TOPO H1: c1->0, c2->1, c3->0
      if (nf1 == 0) contrib = (float)sumsq;
      else contrib = (pcnt >= 1)
        ? ((1.0f - maxp) * (1.0f - maxp) + (float)(sumsq - (double)maxp * (double)maxp))
        : 1.0f;
    }
    atomicAdd(out, contrib * 0.25f);         // / B, B = 4
  }
}

extern "C" void kernel_launch(void* const* d_in, const int* in_sizes, int n_in,
                              void* d_out, int out_size, void* d_ws, size_t ws_size,
                              hipStream_t stream) {
  const float* x = (const float*)d_in[0];
  float* out = (float*)d_out;
  ph_zero_kernel<<<1, 1, 0, stream>>>(out);
  ph_pass_kernel<<<24, NT, 0, stream>>>(x, out);
}

// Round 7
// 411.366 us; speedup vs baseline: 19.4583x; 1.6064x over previous
//
#include <hip/hip_runtime.h>

#define NPIX 4096
#define NT 1024
#define PPT (NPIX / NT)   // 4 per thread
#define EMPTY 0xFFFFFFFFu

__global__ void ph_zero_kernel(float* out) { out[0] = 0.0f; }

__device__ __forceinline__ float kval(unsigned k) {
  unsigned u = (k & 0x80000000u) ? (k & 0x7FFFFFFFu) : ~k;
  return __uint_as_float(u);
}

__global__ __launch_bounds__(NT) void ph_pass_kernel(const float* __restrict__ x,
                                                     float* __restrict__ out) {
  // One 64 KB pool, phase-aliased:
  //  [0,32K)  : hash (hkey 16K | hval 16K)  ->  sorted edge list (u64)
  //  [32K,48K): key32 u32[4096]             ->  clobbered by node records
  //  [48K,56K): label u16[4096]             ->  clobbered by node records
  //  [32K,64K): node u64[4096] = creatorKey<<32 | parent   (Kruskal phase)
  __shared__ unsigned long long pool[2 * NPIX];
  __shared__ unsigned wred[32];          // wave staging: [0..15] raw, [16..31] scanned

  unsigned long long* sbuf = pool;
  unsigned* hkey = (unsigned*)pool;
  unsigned* hval = hkey + NPIX;
  unsigned* key32 = (unsigned*)(pool + NPIX);
  unsigned short* label = (unsigned short*)(pool + NPIX + NPIX / 2);
  unsigned long long* node = pool + NPIX;

  const int blk = blockIdx.x;            // 24 blocks: b(4) x c(3) x pass(2)
  const int b = blk / 6;
  const int rem = blk % 6;
  const int c = (rem >> 1) + 1;          // classes 1..3
  const int pass = rem & 1;              // 0 = sublevel 8-conn (H0), 1 = superlevel 4-conn (H1)
  const float* img = x + (size_t)(b * 4 + c) * NPIX;
  const int tid = threadIdx.x;
  const int lane = tid & 63, wid = tid >> 6;
  const int ndirs = pass ? 4 : 8;
  const int drr[8] = {-1, 1, 0, 0, -1, -1, 1, 1};
  const int dcc[8] = { 0, 0,-1, 1, -1,  1, -1, 1};

  // --- phase 1: monotone keys (pass 1 negates); block-min via shfl ---
  unsigned lmin = EMPTY;
  for (int i = tid; i < NPIX; i += NT) {
    float f = img[i];
    if (pass) f = -f;
    unsigned u = __float_as_uint(f);
    unsigned k = (u & 0x80000000u) ? ~u : (u | 0x80000000u);
    key32[i] = k;
    lmin = min(lmin, k);
  }
  for (int off = 32; off > 0; off >>= 1)
    lmin = min(lmin, (unsigned)__shfl_xor((int)lmin, off));
  if (lane == 0) wred[wid] = lmin;
  __syncthreads();                       // also covers key32 writes
  unsigned vmink = wred[0];
  #pragma unroll
  for (int w = 1; w < 16; w++) vmink = min(vmink, wred[w]);

  // --- phase 2: watershed pointers + pointer jumping ---
  for (int i = tid; i < NPIX; i += NT) {
    unsigned long long best = ((unsigned long long)key32[i] << 32) | (unsigned)i;
    int bestnb = i;
    int r = i >> 6, cc = i & 63;
    for (int d = 0; d < ndirs; d++) {
      int rr = r + drr[d], c2 = cc + dcc[d];
      if ((unsigned)rr >= 64u || (unsigned)c2 >= 64u) continue;
      int nb = (rr << 6) | c2;
      unsigned long long pn = ((unsigned long long)key32[nb] << 32) | (unsigned)nb;
      if (pn < best) { best = pn; bestnb = nb; }
    }
    label[i] = (unsigned short)bestnb;
  }
  __syncthreads();
  for (int round = 0; round < 12; round++) {
    for (int i = tid; i < NPIX; i += NT) {
      unsigned short l = label[i];
      label[i] = label[l];               // monotone -> race-safe
    }
    __syncthreads();
  }

  // --- phase 3: hash init — ONLY pool[0..NPIX) (32 KB); key32/label live above ---
  for (int i = tid; i < NPIX; i += NT) pool[i] = ~0ull;    // hkey=hval=EMPTY
  __syncthreads();

  // --- phase 4: inter-basin edges deduped to min weight per basin pair ---
  const int pdr[4] = {1, 0, 1,  1};
  const int pdc[4] = {0, 1, 1, -1};
  const int npd = pass ? 2 : 4;
  for (int i = tid; i < NPIX; i += NT) {
    int r = i >> 6, cc = i & 63;
    unsigned la = label[i];
    unsigned ki = key32[i];
    for (int d = 0; d < npd; d++) {
      int rr = r + pdr[d], c2 = cc + pdc[d];
      if ((unsigned)rr >= 64u || (unsigned)c2 >= 64u) continue;
      int nb = (rr << 6) | c2;
      unsigned lb = label[nb];
      if (lb == la) continue;
      unsigned wkey = max(ki, key32[nb]);                  // weight = max endpoint key
      unsigned pk = la < lb ? ((la << 12) | lb) : ((lb << 12) | la);
      unsigned h = (pk * 2654435761u) >> 20;
      while (true) {
        unsigned old = atomicCAS(&hkey[h], EMPTY, pk);
        if (old == EMPTY || old == pk) { atomicMin(&hval[h], wkey); break; }
        h = (h + 1) & (NPIX - 1);
      }
    }
  }
  __syncthreads();

  // --- phase 5: stage hash + keys into regs; shfl scan; write edges + nodes ---
  unsigned long long item[PPT];
  unsigned mykeys[PPT];
  int cnt = 0;
  #pragma unroll
  for (int q = 0; q < PPT; q++) {
    int s = tid * PPT + q;
    unsigned pk = hkey[s];
    if (pk != EMPTY) item[cnt++] = (((unsigned long long)hval[s]) << 32) | pk;
  }
  #pragma unroll
  for (int t = 0; t < PPT; t++) mykeys[t] = key32[tid + t * NT];
  __syncthreads();                       // all reads of pool[0..56K) done
  unsigned inc = (unsigned)cnt;          // intra-wave inclusive scan
  for (int off = 1; off < 64; off <<= 1) {
    unsigned v = (unsigned)__shfl_up((int)inc, off);
    if (lane >= off) inc += v;
  }
  if (lane == 63) wred[wid] = inc;
  __syncthreads();
  if (wid == 0) {                        // scan the 16 wave totals in wave 0
    unsigned wv = (lane < 16) ? wred[lane] : 0u;
    for (int off = 1; off < 16; off <<= 1) {
      unsigned v = (unsigned)__shfl_up((int)wv, off);
      if (lane >= off) wv += v;
    }
    if (lane < 16) wred[16 + lane] = wv; // inclusive totals
  }
  __syncthreads();
  const int M = (int)wred[31];
  const unsigned wbase = (wid == 0) ? 0u : wred[16 + wid - 1];
  const int base = (int)(wbase + inc - (unsigned)cnt);
  __syncthreads();                       // wred consumed; pool writable
  for (int q = 0; q < cnt; q++) sbuf[base + q] = item[q];
  #pragma unroll
  for (int t = 0; t < PPT; t++) {
    int i = tid + t * NT;
    node[i] = (((unsigned long long)mykeys[t]) << 32) | (unsigned)i;  // singleton
  }
  int S = 256;                           // adaptive sort size
  while (S < M) S <<= 1;
  for (int i = M + tid; i < S; i += NT) sbuf[i] = ~0ull;   // sort pad
  __syncthreads();

  // --- phase 6: bitonic sort S edges ascending by weight key ---
  for (int k = 2; k <= S; k <<= 1) {
    for (int j = k >> 1; j > 0; j >>= 1) {
      for (int i = tid; i < S; i += NT) {
        int ixj = i ^ j;
        if (ixj > i) {
          unsigned long long va = sbuf[i], vb = sbuf[ixj];
          bool up = ((i & k) == 0);
          if ((va > vb) == up) { sbuf[i] = vb; sbuf[ixj] = va; }
        }
      }
      __syncthreads();
    }
  }

  // --- phase 7: wave-parallel Kruskal (wave 0, 64 edges/batch, lane-ordered
  //     speculation fixup) + block-wide flatten every 512 edges ---
  double sumsq = 0.0;
  float maxp = 0.0f;
  int pcnt = 0;
  const int ngroups = (M + 511) >> 9;
  for (int g = 0; g < ngroups; g++) {
    if (wid == 0) {
      for (int bb = 0; bb < 8; bb++) {
        const int e0 = (g << 9) + (bb << 6);
        if (e0 >= M) break;              // wave-uniform
        const int j = e0 + lane;
        const bool act = (j < M);
        unsigned long long e = act ? sbuf[j] : ~0ull;
        const unsigned wk = (unsigned)(e >> 32);
        const unsigned pk = (unsigned)(e & 0xFFFFFFu);
        unsigned xa = EMPTY, xb = EMPTY;
        unsigned long long recA = 0, recB = 0;
        if (act) {
          xa = pk >> 12; xb = pk & 0xFFFu;
          recA = node[xa];
          recB = node[xb];               // both finds' loads overlap across lanes
          while ((unsigned)recA != xa) { xa = (unsigned)recA; recA = node[xa]; }
          while ((unsigned)recB != xb) { xb = (unsigned)recB; recB = node[xb]; }
        }
        unsigned commit_young = EMPTY, commit_elder = 0;
        unsigned long long commit_yrec = 0;
        for (int k = 0; k < 64; k++) {
          // every lane's tentative decision from current (possibly remapped) roots
          const bool tv = act && (xa != xb);
          unsigned t_young, t_elder;
          unsigned long long t_erec, t_yrec;
          if (recA < recB) { t_elder = xa; t_erec = recA; t_young = xb; t_yrec = recB; }
          else             { t_elder = xb; t_erec = recB; t_young = xa; t_yrec = recA; }
          const unsigned by = (unsigned)__shfl((int)(tv ? t_young : EMPTY), k);
          const unsigned be = (unsigned)__shfl((int)t_elder, k);
          const unsigned long long ber = __shfl(t_erec, k);
          if (lane == k && tv) {         // lane k is final: commit its pair
            unsigned ky = (unsigned)(t_yrec >> 32);
            if (wk > ky) {               // strictly positive persistence
              float pers = kval(wk) - kval(ky);
              sumsq += (double)pers * (double)pers;
              maxp = fmaxf(maxp, pers);
              pcnt++;
            }
            commit_young = t_young; commit_elder = t_elder; commit_yrec = t_yrec;
          }
          if (by != EMPTY) {             // lanes after k remap dead root
            if (xa == by) { xa = be; recA = ber; }
            if (xb == by) { xb = be; recB = ber; }
          }
        }
        if (commit_young != EMPTY)       // unique youngs -> parallel writes safe
          node[commit_young] = (commit_yrec & 0xFFFFFFFF00000000ull) | commit_elder;
      }
    }
    __syncthreads();
    for (int i = tid; i < NPIX; i += NT) {   // flatten to depth 1
      unsigned long long rec = node[i];
      unsigned px = (unsigned)rec;
      if (px == (unsigned)i) continue;
      unsigned long long r2 = node[px];
      while ((unsigned)r2 != px) { px = (unsigned)r2; r2 = node[px]; }
      node[i] = (rec & 0xFFFFFFFF00000000ull) | px;
    }
    __syncthreads();
  }
  if (wid == 0) {                        // reduce lane accumulators to lane 0
    for (int off = 32; off > 0; off >>= 1) {
      sumsq += __shfl_xor(sumsq, off);
      maxp = fmaxf(maxp, __shfl_xor(maxp, off));
      pcnt += __shfl_xor(pcnt, off);
    }
  }

  // --- phase 8: loss contribution ---
  if (tid == 0) {
    float contrib;
    if (pass == 0) {
      const int nf0 = (c == 3) ? 2 : 1;      // TOPO H0: c1->1, c2->1, c3->2
      float vmin = kval(vmink);              // essential birth = global min
      if (nf0 == 1) {
        contrib = vmin * vmin + (float)sumsq;
      } else if (pcnt >= 1) {
        contrib = vmin * vmin + (1.0f - maxp) * (1.0f - maxp)
                + (float)(sumsq - (double)maxp * (double)maxp);
      } else {
        contrib = vmin * vmin + 1.0f;
      }
    } else {
      const int nf1 = (c == 2) ? 1 : 0;      // TOPO H1: c1->0, c2->1, c3->0
      if (nf1 == 0) contrib = (float)sumsq;
      else contrib = (pcnt >= 1)
        ? ((1.0f - maxp) * (1.0f - maxp) + (float)(sumsq - (double)maxp * (double)maxp))
        : 1.0f;
    }
    atomicAdd(out, contrib * 0.25f);         // / B, B = 4
  }
}

extern "C" void kernel_launch(void* const* d_in, const int* in_sizes, int n_in,
                              void* d_out, int out_size, void* d_ws, size_t ws_size,
                              hipStream_t stream) {
  const float* x = (const float*)d_in[0];
  float* out = (float*)d_out;
  ph_zero_kernel<<<1, 1, 0, stream>>>(out);
  ph_pass_kernel<<<24, NT, 0, stream>>>(x, out);
}

// Round 8
// 304.454 us; speedup vs baseline: 26.2913x; 1.3512x over previous
//
#include <hip/hip_runtime.h>

#define NPIX 4096
#define NT 1024
#define PPT (NPIX / NT)   // 4 per thread
#define EMPTY 0xFFFFFFFFu

__global__ void ph_zero_kernel(float* out) { out[0] = 0.0f; }

__device__ __forceinline__ float kval(unsigned k) {
  unsigned u = (k & 0x80000000u) ? (k & 0x7FFFFFFFu) : ~k;
  return __uint_as_float(u);
}

__global__ __launch_bounds__(NT) void ph_pass_kernel(const float* __restrict__ x,
                                                     float* __restrict__ out) {
  // One 64 KB pool, phase-aliased:
  //  [0,32K)  : hash (hkey 16K | hval 16K) -> edge sort buffers A|B -> sorted edges
  //  [32K,48K): key32 u32[4096]            -> clobbered by node records
  //  [48K,56K): label u16[4096]            -> clobbered by node records
  //  [32K,64K): node u64[4096] = creatorKey<<32 | parent   (Kruskal phase)
  __shared__ unsigned long long pool[2 * NPIX];
  __shared__ unsigned wred[32];          // wave staging: [0..15] raw, [16..31] scanned
  __shared__ int s_chg[13];              // per-round convergence flags

  unsigned long long* sbuf = pool;
  unsigned* hkey = (unsigned*)pool;
  unsigned* hval = hkey + NPIX;
  unsigned* key32 = (unsigned*)(pool + NPIX);
  unsigned short* label = (unsigned short*)(pool + NPIX + NPIX / 2);
  unsigned long long* node = pool + NPIX;

  const int blk = blockIdx.x;            // 24 blocks: b(4) x c(3) x pass(2)
  const int b = blk / 6;
  const int rem = blk % 6;
  const int c = (rem >> 1) + 1;          // classes 1..3
  const int pass = rem & 1;              // 0 = sublevel 8-conn (H0), 1 = superlevel 4-conn (H1)
  const float* img = x + (size_t)(b * 4 + c) * NPIX;
  const int tid = threadIdx.x;
  const int lane = tid & 63, wid = tid >> 6;
  const int ndirs = pass ? 4 : 8;
  const int drr[8] = {-1, 1, 0, 0, -1, -1, 1, 1};
  const int dcc[8] = { 0, 0,-1, 1, -1,  1, -1, 1};

  // --- phase 1: monotone keys (pass 1 negates); hash init folded; block-min ---
  if (tid < 13) s_chg[tid] = 0;
  unsigned lmin = EMPTY;
  for (int i = tid; i < NPIX; i += NT) {
    float f = img[i];
    if (pass) f = -f;
    unsigned u = __float_as_uint(f);
    unsigned k = (u & 0x80000000u) ? ~u : (u | 0x80000000u);
    key32[i] = k;
    pool[i] = ~0ull;                     // hkey/hval = EMPTY (region [0,32K))
    lmin = min(lmin, k);
  }
  for (int off = 32; off > 0; off >>= 1)
    lmin = min(lmin, (unsigned)__shfl_xor((int)lmin, off));
  if (lane == 0) wred[wid] = lmin;
  __syncthreads();
  unsigned vmink = wred[0];
  #pragma unroll
  for (int w = 1; w < 16; w++) vmink = min(vmink, wred[w]);

  // --- phase 2: watershed pointers + converging pointer jumping ---
  for (int i = tid; i < NPIX; i += NT) {
    unsigned long long best = ((unsigned long long)key32[i] << 32) | (unsigned)i;
    int bestnb = i;
    int r = i >> 6, cc = i & 63;
    for (int d = 0; d < ndirs; d++) {
      int rr = r + drr[d], c2 = cc + dcc[d];
      if ((unsigned)rr >= 64u || (unsigned)c2 >= 64u) continue;
      int nb = (rr << 6) | c2;
      unsigned long long pn = ((unsigned long long)key32[nb] << 32) | (unsigned)nb;
      if (pn < best) { best = pn; bestnb = nb; }
    }
    label[i] = (unsigned short)bestnb;
  }
  __syncthreads();
  for (int round = 0; round < 12; round++) {   // >= doubling per round; early exit
    bool changed = false;
    for (int i = tid; i < NPIX; i += NT) {
      unsigned short l = label[i];
      unsigned short l2 = label[l];
      if (l2 != l) { label[i] = l2; changed = true; }
    }
    if (changed) s_chg[round] = 1;
    __syncthreads();
    if (!s_chg[round]) break;                  // block-uniform
  }

  // --- phase 3: inter-basin edges deduped to min weight per basin pair ---
  const int pdr[4] = {1, 0, 1,  1};
  const int pdc[4] = {0, 1, 1, -1};
  const int npd = pass ? 2 : 4;
  for (int i = tid; i < NPIX; i += NT) {
    int r = i >> 6, cc = i & 63;
    unsigned la = label[i];
    unsigned ki = key32[i];
    for (int d = 0; d < npd; d++) {
      int rr = r + pdr[d], c2 = cc + pdc[d];
      if ((unsigned)rr >= 64u || (unsigned)c2 >= 64u) continue;
      int nb = (rr << 6) | c2;
      unsigned lb = label[nb];
      if (lb == la) continue;
      unsigned wkey = max(ki, key32[nb]);      // weight = max endpoint key
      unsigned pk = la < lb ? ((la << 12) | lb) : ((lb << 12) | la);
      unsigned h = (pk * 2654435761u) >> 20;
      while (true) {
        unsigned old = atomicCAS(&hkey[h], EMPTY, pk);
        if (old == EMPTY || old == pk) { atomicMin(&hval[h], wkey); break; }
        h = (h + 1) & (NPIX - 1);
      }
    }
  }
  __syncthreads();

  // --- phase 4: stage hash + keys into regs; shfl scan; write edges + nodes ---
  unsigned long long item[PPT];
  unsigned mykeys[PPT];
  int cnt = 0;
  #pragma unroll
  for (int q = 0; q < PPT; q++) {
    int s = tid * PPT + q;
    unsigned pk = hkey[s];
    if (pk != EMPTY) item[cnt++] = (((unsigned long long)hval[s]) << 32) | pk;
  }
  #pragma unroll
  for (int t = 0; t < PPT; t++) mykeys[t] = key32[tid + t * NT];
  __syncthreads();                       // all reads of pool[0..56K) done
  unsigned inc = (unsigned)cnt;          // intra-wave inclusive scan
  for (int off = 1; off < 64; off <<= 1) {
    unsigned v = (unsigned)__shfl_up((int)inc, off);
    if (lane >= off) inc += v;
  }
  if (lane == 63) wred[wid] = inc;
  __syncthreads();
  if (wid == 0) {                        // scan the 16 wave totals in wave 0
    unsigned wv = (lane < 16) ? wred[lane] : 0u;
    for (int off = 1; off < 16; off <<= 1) {
      unsigned v = (unsigned)__shfl_up((int)wv, off);
      if (lane >= off) wv += v;
    }
    if (lane < 16) wred[16 + lane] = wv;
  }
  __syncthreads();
  const int M = (int)wred[31];
  const unsigned wbase = (wid == 0) ? 0u : wred[16 + wid - 1];
  const int base = (int)(wbase + inc - (unsigned)cnt);
  __syncthreads();                       // wred consumed; pool writable
  for (int q = 0; q < cnt; q++) sbuf[base + q] = item[q];
  #pragma unroll
  for (int t = 0; t < PPT; t++) {
    int i = tid + t * NT;
    node[i] = (((unsigned long long)mykeys[t]) << 32) | (unsigned)i;  // singleton
  }
  for (int i = M + tid; i < NPIX; i += NT) sbuf[i] = ~0ull;           // pad
  __syncthreads();

  // --- phase 5: sort edges ascending by weight key ---
  if (M <= 2048) {
    // Hybrid bitonic on 2048: j<64 via shfl_xor (no barrier); j in [64,512] via
    // ping-pong LDS (A=pool[0..2048), B=pool[2048..4096)); j=1024 in-thread.
    unsigned long long v0 = sbuf[tid];
    unsigned long long v1 = sbuf[tid + 1024];
    const int i0 = tid, i1 = tid + 1024;
    auto regstage = [&](int k, int j) {
      unsigned long long p0 = __shfl_xor(v0, j);
      unsigned long long p1 = __shfl_xor(v1, j);
      bool m0 = (((i0 & j) == 0) == ((i0 & k) == 0));
      bool m1 = (((i1 & j) == 0) == ((i1 & k) == 0));
      v0 = m0 ? (v0 < p0 ? v0 : p0) : (v0 > p0 ? v0 : p0);
      v1 = m1 ? (v1 < p1 ? v1 : p1) : (v1 > p1 ? v1 : p1);
    };
    int buf = 1;
    for (int k = 2; k <= 64; k <<= 1)
      for (int j = k >> 1; j >= 1; j >>= 1) regstage(k, j);
    for (int k = 128; k <= 2048; k <<= 1) {
      for (int j = k >> 1; j >= 64; j >>= 1) {
        if (j == 1024) {                 // partner is own other element; ascending
          if (v0 > v1) { unsigned long long t = v0; v0 = v1; v1 = t; }
        } else {
          unsigned long long* bp = pool + (buf ? 2048 : 0);
          bp[tid] = v0; bp[tid + 1024] = v1;
          __syncthreads();
          unsigned long long p0 = bp[tid ^ j];
          unsigned long long p1 = bp[(tid ^ j) + 1024];
          bool m0 = (((i0 & j) == 0) == ((i0 & k) == 0));
          bool m1 = (((i1 & j) == 0) == ((i1 & k) == 0));
          v0 = m0 ? (v0 < p0 ? v0 : p0) : (v0 > p0 ? v0 : p0);
          v1 = m1 ? (v1 < p1 ? v1 : p1) : (v1 > p1 ? v1 : p1);
          buf ^= 1;
        }
      }
      for (int j = 32; j >= 1; j >>= 1) regstage(k, j);
    }
    sbuf[tid] = v0; sbuf[tid + 1024] = v1;   // final: back to A for Kruskal
    __syncthreads();
  } else {
    // fallback: in-place bitonic on 4096 (never hit for this input shape)
    for (int k = 2; k <= NPIX; k <<= 1) {
      for (int j = k >> 1; j > 0; j >>= 1) {
        for (int i = tid; i < NPIX; i += NT) {
          int ixj = i ^ j;
          if (ixj > i) {
            unsigned long long va = sbuf[i], vb = sbuf[ixj];
            bool up = ((i & k) == 0);
            if ((va > vb) == up) { sbuf[i] = vb; sbuf[ixj] = va; }
          }
        }
        __syncthreads();
      }
    }
  }

  // --- phase 6: wave-parallel Kruskal (wave 0, ballot-ordered fixup) ---
  double sumsq = 0.0;
  float maxp = 0.0f;
  int pcnt = 0;
  const int ngroups = (M + 511) >> 9;
  for (int g = 0; g < ngroups; g++) {
    if (wid == 0) {
      for (int bb = 0; bb < 8; bb++) {
        const int e0 = (g << 9) + (bb << 6);
        if (e0 >= M) break;              // wave-uniform
        const int j = e0 + lane;
        const bool act = (j < M);
        unsigned long long e = act ? sbuf[j] : ~0ull;
        const unsigned wk = (unsigned)(e >> 32);
        const unsigned pk = (unsigned)(e & 0xFFFFFFu);
        unsigned xa = EMPTY, xb = EMPTY;
        unsigned long long recA = 0, recB = 0;
        if (act) {
          xa = pk >> 12; xb = pk & 0xFFFu;
          recA = node[xa];
          recB = node[xb];               // finds' loads overlap across lanes
          while ((unsigned)recA != xa) { xa = (unsigned)recA; recA = node[xa]; }
          while ((unsigned)recB != xb) { xb = (unsigned)recB; recB = node[xb]; }
        }
        bool tv = act && (xa != xb);
        unsigned long long mask = __ballot(tv);
        while (mask) {
          const int k = __builtin_ctzll(mask);   // lowest pending lane = edge order
          unsigned t_elder, t_young;
          unsigned long long t_erec, t_yrec;
          if (recA < recB) { t_elder = xa; t_erec = recA; t_young = xb; t_yrec = recB; }
          else             { t_elder = xb; t_erec = recB; t_young = xa; t_yrec = recA; }
          const unsigned by = (unsigned)__shfl((int)t_young, k);
          const unsigned be = (unsigned)__shfl((int)t_elder, k);
          const unsigned long long ber = __shfl(t_erec, k);
          if (lane == k) {               // commit: unique young, safe write
            const unsigned ky = (unsigned)(t_yrec >> 32);
            if (wk > ky) {               // strictly positive persistence
              float pers = kval(wk) - kval(ky);
              sumsq += (double)pers * (double)pers;
              maxp = fmaxf(maxp, pers);
              pcnt++;
            }
            node[t_young] = (t_yrec & 0xFFFFFFFF00000000ull) | t_elder;
            tv = false;
          } else if (tv) {               // remap dead root
            if (xa == by) { xa = be; recA = ber; }
            if (xb == by) { xb = be; recB = ber; }
            tv = (xa != xb);
          }
          mask = __ballot(tv);
        }
      }
    }
    __syncthreads();
    for (int i = tid; i < NPIX; i += NT) {   // flatten to depth 1
      unsigned long long rec = node[i];
      unsigned px = (unsigned)rec;
      if (px == (unsigned)i) continue;
      unsigned long long r2 = node[px];
      while ((unsigned)r2 != px) { px = (unsigned)r2; r2 = node[px]; }
      node[i] = (rec & 0xFFFFFFFF00000000ull) | px;
    }
    __syncthreads();
  }
  if (wid == 0) {                        // reduce lane accumulators to lane 0
    for (int off = 32; off > 0; off >>= 1) {
      sumsq += __shfl_xor(sumsq, off);
      maxp = fmaxf(maxp, __shfl_xor(maxp, off));
      pcnt += __shfl_xor(pcnt, off);
    }
  }

  // --- phase 7: loss contribution ---
  if (tid == 0) {
    float contrib;
    if (pass == 0) {
      const int nf0 = (c == 3) ? 2 : 1;      // TOPO H0: c1->1, c2->1, c3->2
      float vmin = kval(vmink);              // essential birth = global min
      if (nf0 == 1) {
        contrib = vmin * vmin + (float)sumsq;
      } else if (pcnt >= 1) {
        contrib = vmin * vmin + (1.0f - maxp) * (1.0f - maxp)
                + (float)(sumsq - (double)maxp * (double)maxp);
      } else {
        contrib = vmin * vmin + 1.0f;
      }
    } else {
      const int nf1 = (c == 2) ? 1 : 0;      // TOPO H1: c1->0, c2->1, c3->0
      if (nf1 == 0) contrib = (float)sumsq;
      else contrib = (pcnt >= 1)
        ? ((1.0f - maxp) * (1.0f - maxp) + (float)(sumsq - (double)maxp * (double)maxp))
        : 1.0f;
    }
    atomicAdd(out, contrib * 0.25f);         // / B, B = 4
  }
}

extern "C" void kernel_launch(void* const* d_in, const int* in_sizes, int n_in,
                              void* d_out, int out_size, void* d_ws, size_t ws_size,
                              hipStream_t stream) {
  const float* x = (const float*)d_in[0];
  float* out = (float*)d_out;
  ph_zero_kernel<<<1, 1, 0, stream>>>(out);
  ph_pass_kernel<<<24, NT, 0, stream>>>(x, out);
}

// Round 9
// 303.379 us; speedup vs baseline: 26.3844x; 1.0035x over previous
//
#include <hip/hip_runtime.h>

#define NPIX 4096
#define NT 1024
#define PPT (NPIX / NT)   // 4 per thread
#define EMPTY 0xFFFFFFFFu
#define FLAGMAGIC 0x00C0FFEEu

__global__ void ph_zero_kernel(float* out) { out[0] = 0.0f; }

__device__ __forceinline__ float kval(unsigned k) {
  unsigned u = (k & 0x80000000u) ? (k & 0x7FFFFFFFu) : ~k;
  return __uint_as_float(u);
}

__global__ __launch_bounds__(NT) void ph_pass_kernel(const float* __restrict__ x,
                                                     float* __restrict__ out,
                                                     unsigned long long* __restrict__ ws64,
                                                     int use_ws) {
  // One 64 KB pool, phase-aliased:
  //  [0,32K)  : hash (hkey 16K | hval 16K) -> edge sort buffers A|B -> sorted edges
  //  [32K,48K): key32 u32[4096]            -> clobbered by node records
  //  [48K,56K): label u16[4096]            -> clobbered by node records
  //  [32K,64K): node u64[4096] = creatorKey<<32 | parent   (Kruskal phase)
  __shared__ unsigned long long pool[2 * NPIX];
  __shared__ unsigned long long wred[32];  // wave staging: [0..15] raw, [16..31] scanned
  __shared__ unsigned short blist[2048];   // basin-min pixel list (max 2048, 4-conn)
  __shared__ int s_chg[13];                // per-round convergence flags

  unsigned long long* sbuf = pool;
  unsigned* hkey = (unsigned*)pool;
  unsigned* hval = hkey + NPIX;
  unsigned* key32 = (unsigned*)(pool + NPIX);
  unsigned short* label = (unsigned short*)(pool + NPIX + NPIX / 2);
  unsigned long long* node = pool + NPIX;

  const int blk = blockIdx.x;            // 24 blocks: b(4) x c(3) x pass(2)
  const int b = blk / 6;
  const int rem = blk % 6;
  const int c = (rem >> 1) + 1;          // classes 1..3
  const int pass = rem & 1;              // 0 = sublevel 8-conn (H0), 1 = superlevel 4-conn (H1)
  const float* img = x + (size_t)(b * 4 + c) * NPIX;
  const int tid = threadIdx.x;
  const int lane = tid & 63, wid = tid >> 6;
  const int ndirs = pass ? 4 : 8;
  const int drr[8] = {-1, 1, 0, 0, -1, -1, 1, 1};
  const int dcc[8] = { 0, 0,-1, 1, -1,  1, -1, 1};

  // --- phase 1: monotone keys (pass 1 negates); hash init folded; block-min ---
  if (tid < 13) s_chg[tid] = 0;
  unsigned lmin = EMPTY;
  for (int i = tid; i < NPIX; i += NT) {
    float f = img[i];
    if (pass) f = -f;
    unsigned u = __float_as_uint(f);
    unsigned k = (u & 0x80000000u) ? ~u : (u | 0x80000000u);
    key32[i] = k;
    pool[i] = ~0ull;                     // hkey/hval = EMPTY (region [0,32K))
    lmin = min(lmin, k);
  }
  for (int off = 32; off > 0; off >>= 1)
    lmin = min(lmin, (unsigned)__shfl_xor((int)lmin, off));
  if (lane == 0) wred[wid] = lmin;
  __syncthreads();
  unsigned vmink = (unsigned)wred[0];
  #pragma unroll
  for (int w = 1; w < 16; w++) vmink = min(vmink, (unsigned)wred[w]);

  // --- phase 2: watershed pointers + converging pointer jumping ---
  for (int i = tid; i < NPIX; i += NT) {
    unsigned long long best = ((unsigned long long)key32[i] << 32) | (unsigned)i;
    int bestnb = i;
    int r = i >> 6, cc = i & 63;
    for (int d = 0; d < ndirs; d++) {
      int rr = r + drr[d], c2 = cc + dcc[d];
      if ((unsigned)rr >= 64u || (unsigned)c2 >= 64u) continue;
      int nb = (rr << 6) | c2;
      unsigned long long pn = ((unsigned long long)key32[nb] << 32) | (unsigned)nb;
      if (pn < best) { best = pn; bestnb = nb; }
    }
    label[i] = (unsigned short)bestnb;
  }
  __syncthreads();
  for (int round = 0; round < 12; round++) {   // >= doubling per round; early exit
    bool changed = false;
    for (int i = tid; i < NPIX; i += NT) {
      unsigned short l = label[i];
      unsigned short l2 = label[l];
      if (l2 != l) { label[i] = l2; changed = true; }
    }
    if (changed) s_chg[round] = 1;
    __syncthreads();
    if (!s_chg[round]) break;                  // block-uniform
  }

  // --- phase 3: inter-basin edges deduped to min weight per basin pair ---
  const int pdr[4] = {1, 0, 1,  1};
  const int pdc[4] = {0, 1, 1, -1};
  const int npd = pass ? 2 : 4;
  for (int i = tid; i < NPIX; i += NT) {
    int r = i >> 6, cc = i & 63;
    unsigned la = label[i];
    unsigned ki = key32[i];
    for (int d = 0; d < npd; d++) {
      int rr = r + pdr[d], c2 = cc + pdc[d];
      if ((unsigned)rr >= 64u || (unsigned)c2 >= 64u) continue;
      int nb = (rr << 6) | c2;
      unsigned lb = label[nb];
      if (lb == la) continue;
      unsigned wkey = max(ki, key32[nb]);      // weight = max endpoint key
      unsigned pk = la < lb ? ((la << 12) | lb) : ((lb << 12) | la);
      unsigned h = (pk * 2654435761u) >> 20;
      while (true) {
        unsigned old = atomicCAS(&hkey[h], EMPTY, pk);
        if (old == EMPTY || old == pk) { atomicMin(&hval[h], wkey); break; }
        h = (h + 1) & (NPIX - 1);
      }
    }
  }
  __syncthreads();

  // --- phase 4: stage hash+keys+basin flags; ONE packed u64 scan (edges|basins);
  //     write edges, basin list, node records ---
  unsigned long long item[PPT];
  unsigned mykeys[PPT];
  int cnt = 0, bcnt = 0, bmask = 0;
  #pragma unroll
  for (int q = 0; q < PPT; q++) {
    int s = tid * PPT + q;
    unsigned pk = hkey[s];
    if (pk != EMPTY) item[cnt++] = (((unsigned long long)hval[s]) << 32) | pk;
  }
  #pragma unroll
  for (int t = 0; t < PPT; t++) {
    int i = tid + t * NT;
    mykeys[t] = key32[i];
    if (label[i] == (unsigned short)i) { bmask |= 1 << t; bcnt++; }
  }
  __syncthreads();                       // all reads of pool[0..56K) done
  unsigned long long inc2 = ((unsigned long long)cnt << 32) | (unsigned)bcnt;
  for (int off = 1; off < 64; off <<= 1) {   // intra-wave inclusive scan (both counts)
    unsigned long long v = __shfl_up(inc2, off);
    if (lane >= off) inc2 += v;
  }
  if (lane == 63) wred[wid] = inc2;
  __syncthreads();
  if (wid == 0) {                        // scan the 16 wave totals in wave 0
    unsigned long long wv = (lane < 16) ? wred[lane] : 0ull;
    for (int off = 1; off < 16; off <<= 1) {
      unsigned long long v = __shfl_up(wv, off);
      if (lane >= off) wv += v;
    }
    if (lane < 16) wred[16 + lane] = wv;
  }
  __syncthreads();
  const unsigned long long tot = wred[31];
  const int M = (int)(tot >> 32);
  const int NB = (int)(tot & 0xFFFFFFFFull);
  const unsigned long long wbase = (wid == 0) ? 0ull : wred[16 + wid - 1];
  const int base = (int)((wbase >> 32) + (inc2 >> 32)) - cnt;
  int bbase = (int)((wbase & 0xFFFFFFFFull) + (inc2 & 0xFFFFFFFFull)) - bcnt;
  __syncthreads();                       // wred consumed; pool writable
  for (int q = 0; q < cnt; q++) sbuf[base + q] = item[q];
  #pragma unroll
  for (int t = 0; t < PPT; t++) {
    int i = tid + t * NT;
    node[i] = (((unsigned long long)mykeys[t]) << 32) | (unsigned)i;  // singleton
    if (bmask & (1 << t)) blist[bbase++] = (unsigned short)i;
  }
  for (int i = M + tid; i < NPIX; i += NT) sbuf[i] = ~0ull;           // pad
  __syncthreads();

  // --- phase 5: sort edges ascending by weight key ---
  if (M <= 2048) {
    // Hybrid bitonic on 2048: j<64 via shfl_xor (no barrier); j in [64,512] via
    // ping-pong LDS (A=pool[0..2048), B=pool[2048..4096)); j=1024 in-thread.
    unsigned long long v0 = sbuf[tid];
    unsigned long long v1 = sbuf[tid + 1024];
    const int i0 = tid, i1 = tid + 1024;
    auto regstage = [&](int k, int j) {
      unsigned long long p0 = __shfl_xor(v0, j);
      unsigned long long p1 = __shfl_xor(v1, j);
      bool m0 = (((i0 & j) == 0) == ((i0 & k) == 0));
      bool m1 = (((i1 & j) == 0) == ((i1 & k) == 0));
      v0 = m0 ? (v0 < p0 ? v0 : p0) : (v0 > p0 ? v0 : p0);
      v1 = m1 ? (v1 < p1 ? v1 : p1) : (v1 > p1 ? v1 : p1);
    };
    int buf = 1;
    for (int k = 2; k <= 64; k <<= 1)
      for (int j = k >> 1; j >= 1; j >>= 1) regstage(k, j);
    for (int k = 128; k <= 2048; k <<= 1) {
      for (int j = k >> 1; j >= 64; j >>= 1) {
        if (j == 1024) {                 // partner is own other element; ascending
          if (v0 > v1) { unsigned long long t = v0; v0 = v1; v1 = t; }
        } else {
          unsigned long long* bp = pool + (buf ? 2048 : 0);
          bp[tid] = v0; bp[tid + 1024] = v1;
          __syncthreads();
          unsigned long long p0 = bp[tid ^ j];
          unsigned long long p1 = bp[(tid ^ j) + 1024];
          bool m0 = (((i0 & j) == 0) == ((i0 & k) == 0));
          bool m1 = (((i1 & j) == 0) == ((i1 & k) == 0));
          v0 = m0 ? (v0 < p0 ? v0 : p0) : (v0 > p0 ? v0 : p0);
          v1 = m1 ? (v1 < p1 ? v1 : p1) : (v1 > p1 ? v1 : p1);
          buf ^= 1;
        }
      }
      for (int j = 32; j >= 1; j >>= 1) regstage(k, j);
    }
    sbuf[tid] = v0; sbuf[tid + 1024] = v1;   // final: back to A for Kruskal
    __syncthreads();
  } else {
    // fallback: in-place bitonic on 4096 (never hit for this input shape)
    for (int k = 2; k <= NPIX; k <<= 1) {
      for (int j = k >> 1; j > 0; j >>= 1) {
        for (int i = tid; i < NPIX; i += NT) {
          int ixj = i ^ j;
          if (ixj > i) {
            unsigned long long va = sbuf[i], vb = sbuf[ixj];
            bool up = ((i & k) == 0);
            if ((va > vb) == up) { sbuf[i] = vb; sbuf[ixj] = va; }
          }
        }
        __syncthreads();
      }
    }
  }

  // --- phase 6: wave-parallel Kruskal (wave 0, ballot-ordered fixup)
  //     + basin-only flatten every 512 edges ---
  double sumsq = 0.0;
  float maxp = 0.0f;
  int pcnt = 0;
  const int ngroups = (M + 511) >> 9;
  for (int g = 0; g < ngroups; g++) {
    if (wid == 0) {
      for (int bb = 0; bb < 8; bb++) {
        const int e0 = (g << 9) + (bb << 6);
        if (e0 >= M) break;              // wave-uniform
        const int j = e0 + lane;
        const bool act = (j < M);
        unsigned long long e = act ? sbuf[j] : ~0ull;
        const unsigned wk = (unsigned)(e >> 32);
        const unsigned pk = (unsigned)(e & 0xFFFFFFu);
        unsigned xa = EMPTY, xb = EMPTY;
        unsigned long long recA = 0, recB = 0;
        if (act) {
          xa = pk >> 12; xb = pk & 0xFFFu;
          recA = node[xa];
          recB = node[xb];               // finds' loads overlap across lanes
          while ((unsigned)recA != xa) { xa = (unsigned)recA; recA = node[xa]; }
          while ((unsigned)recB != xb) { xb = (unsigned)recB; recB = node[xb]; }
        }
        bool tv = act && (xa != xb);
        unsigned long long mask = __ballot(tv);
        while (mask) {
          const int k = __builtin_ctzll(mask);   // lowest pending lane = edge order
          unsigned t_elder, t_young;
          unsigned long long t_erec, t_yrec;
          if (recA < recB) { t_elder = xa; t_erec = recA; t_young = xb; t_yrec = recB; }
          else             { t_elder = xb; t_erec = recB; t_young = xa; t_yrec = recA; }
          const unsigned by = (unsigned)__shfl((int)t_young, k);
          const unsigned be = (unsigned)__shfl((int)t_elder, k);
          const unsigned long long ber = __shfl(t_erec, k);
          if (lane == k) {               // commit: unique young, safe write
            const unsigned ky = (unsigned)(t_yrec >> 32);
            if (wk > ky) {               // strictly positive persistence
              float pers = kval(wk) - kval(ky);
              sumsq += (double)pers * (double)pers;
              maxp = fmaxf(maxp, pers);
              pcnt++;
            }
            node[t_young] = (t_yrec & 0xFFFFFFFF00000000ull) | t_elder;
            tv = false;
          } else if (tv) {               // remap dead root
            if (xa == by) { xa = be; recA = ber; }
            if (xb == by) { xb = be; recB = ber; }
            tv = (xa != xb);
          }
          mask = __ballot(tv);
        }
      }
    }
    __syncthreads();
    for (int i = tid; i < NB; i += NT) {     // flatten basins only (NB <= 2048)
      const int p0 = blist[i];
      unsigned long long rec = node[p0];
      unsigned px = (unsigned)rec;
      if (px == (unsigned)p0) continue;
      unsigned long long r2 = node[px];
      while ((unsigned)r2 != px) { px = (unsigned)r2; r2 = node[px]; }
      node[p0] = (rec & 0xFFFFFFFF00000000ull) | px;
    }
    __syncthreads();
  }
  if (wid == 0) {                        // reduce lane accumulators to lane 0
    for (int off = 32; off > 0; off >>= 1) {
      sumsq += __shfl_xor(sumsq, off);
      maxp = fmaxf(maxp, __shfl_xor(maxp, off));
      pcnt += __shfl_xor(pcnt, off);
    }
  }

  // --- phase 7: per-block contribution ---
  float contrib = 0.0f;
  if (tid == 0) {
    if (pass == 0) {
      const int nf0 = (c == 3) ? 2 : 1;      // TOPO H0: c1->1, c2->1, c3->2
      float vmin = kval(vmink);              // essential birth = global min
      if (nf0 == 1) {
        contrib = vmin * vmin + (float)sumsq;
      } else if (pcnt >= 1) {
        contrib = vmin * vmin + (1.0f - maxp) * (1.0f - maxp)
                + (float)(sumsq - (double)maxp * (double)maxp);
      } else {
        contrib = vmin * vmin + 1.0f;
      }
    } else {
      const int nf1 = (c == 2) ? 1 : 0;      // TOPO H1: c1->0, c2->1, c3->0
      if (nf1 == 0) contrib = (float)sumsq;
      else contrib = (pcnt >= 1)
        ? ((1.0f - maxp) * (1.0f - maxp) + (float)(sumsq - (double)maxp * (double)maxp))
        : 1.0f;
    }
    contrib *= 0.25f;                        // / B, B = 4
    if (use_ws) {
      // publish (value<<32 | magic) in one device-scope atomic — no fence needed
      atomicExch(&ws64[blk],
                 (((unsigned long long)__float_as_uint(contrib)) << 32) | FLAGMAGIC);
    } else {
      atomicAdd(out, contrib);               // out pre-zeroed by ph_zero_kernel
    }
  }
  // --- block 0 wave 0: gather all 24 contributions, write out ---
  if (use_ws && blk == 0 && wid == 0) {
    float v = 0.0f;
    if (lane < 24) {
      while (true) {
        unsigned long long r = atomicAdd(&ws64[lane], 0ull);  // device-coherent read
        if ((unsigned)r == FLAGMAGIC) { v = __uint_as_float((unsigned)(r >> 32)); break; }
      }
    }
    for (int off = 32; off > 0; off >>= 1) v += __shfl_xor(v, off);
    if (lane == 0) out[0] = v;
  }
}

extern "C" void kernel_launch(void* const* d_in, const int* in_sizes, int n_in,
                              void* d_out, int out_size, void* d_ws, size_t ws_size,
                              hipStream_t stream) {
  const float* x = (const float*)d_in[0];
  float* out = (float*)d_out;
  if (ws_size >= 24 * sizeof(unsigned long long)) {
    ph_pass_kernel<<<24, NT, 0, stream>>>(x, out, (unsigned long long*)d_ws, 1);
  } else {
    ph_zero_kernel<<<1, 1, 0, stream>>>(out);
    ph_pass_kernel<<<24, NT, 0, stream>>>(x, out, nullptr, 0);
  }
}

// Round 11
// 204.003 us; speedup vs baseline: 39.2371x; 1.4871x over previous
//
#include <hip/hip_runtime.h>

#define NPIX 4096
#define NT 1024
#define PPT (NPIX / NT)   // 4 per thread
#define EMPTY 0xFFFFFFFFu
#define FLAGMAGIC 0x00C0FFEEu

__global__ void ph_zero_kernel(float* out) { out[0] = 0.0f; }

__device__ __forceinline__ float kval(unsigned k) {
  unsigned u = (k & 0x80000000u) ? (k & 0x7FFFFFFFu) : ~k;
  return __uint_as_float(u);
}

__device__ __forceinline__ void memfence_compiler() {
  __asm__ volatile("" ::: "memory");
  __builtin_amdgcn_sched_barrier(0);
}

__global__ __launch_bounds__(NT) void ph_pass_kernel(const float* __restrict__ x,
                                                     float* __restrict__ out,
                                                     unsigned long long* __restrict__ ws64,
                                                     int use_ws) {
  // One 64 KB pool, phase-aliased:
  //  [0,32K)  : hash (hkey 16K | hval 16K) -> edge sort buffers A|B -> sorted edges
  //  [32K,48K): key32 u32[4096]            -> clobbered by node records
  //  [48K,56K): label u16[4096]            -> clobbered by node records
  //  [32K,64K): node u64[4096] = creatorKey<<32 | parent   (Kruskal phase)
  __shared__ unsigned long long pool[2 * NPIX];
  __shared__ unsigned long long wred[32];  // wave staging: [0..15] raw, [16..31] scanned
  __shared__ unsigned short blist[2048];   // basin-min pixel list (max 2048, 4-conn)
  __shared__ unsigned claim[NPIX];         // 16 KB: seq-tagged claim cells (no reset)
  __shared__ int s_chg[13];                // per-round convergence flags

  unsigned long long* sbuf = pool;
  unsigned* hkey = (unsigned*)pool;
  unsigned* hval = hkey + NPIX;
  unsigned* key32 = (unsigned*)(pool + NPIX);
  unsigned short* label = (unsigned short*)(pool + NPIX + NPIX / 2);
  unsigned long long* node = pool + NPIX;

  const int blk = blockIdx.x;            // 24 blocks: b(4) x c(3) x pass(2)
  const int b = blk / 6;
  const int rem = blk % 6;
  const int c = (rem >> 1) + 1;          // classes 1..3
  const int pass = rem & 1;              // 0 = sublevel 8-conn (H0), 1 = superlevel 4-conn (H1)
  const float* img = x + (size_t)(b * 4 + c) * NPIX;
  const int tid = threadIdx.x;
  const int lane = tid & 63, wid = tid >> 6;
  const int ndirs = pass ? 4 : 8;
  const int drr[8] = {-1, 1, 0, 0, -1, -1, 1, 1};
  const int dcc[8] = { 0, 0,-1, 1, -1,  1, -1, 1};

  // --- phase 1: monotone keys (pass 1 negates); hash+claim init folded; min ---
  if (tid < 13) s_chg[tid] = 0;
  unsigned lmin = EMPTY;
  for (int i = tid; i < NPIX; i += NT) {
    float f = img[i];
    if (pass) f = -f;
    unsigned u = __float_as_uint(f);
    unsigned k = (u & 0x80000000u) ? ~u : (u | 0x80000000u);
    key32[i] = k;
    pool[i] = ~0ull;                     // hkey/hval = EMPTY (region [0,32K))
    claim[i] = 0;
    lmin = min(lmin, k);
  }
  for (int off = 32; off > 0; off >>= 1)
    lmin = min(lmin, (unsigned)__shfl_xor((int)lmin, off));
  if (lane == 0) wred[wid] = lmin;
  __syncthreads();
  unsigned vmink = (unsigned)wred[0];
  #pragma unroll
  for (int w = 1; w < 16; w++) vmink = min(vmink, (unsigned)wred[w]);

  // --- phase 2: watershed pointers + converging pointer jumping ---
  for (int i = tid; i < NPIX; i += NT) {
    unsigned long long best = ((unsigned long long)key32[i] << 32) | (unsigned)i;
    int bestnb = i;
    int r = i >> 6, cc = i & 63;
    for (int d = 0; d < ndirs; d++) {
      int rr = r + drr[d], c2 = cc + dcc[d];
      if ((unsigned)rr >= 64u || (unsigned)c2 >= 64u) continue;
      int nb = (rr << 6) | c2;
      unsigned long long pn = ((unsigned long long)key32[nb] << 32) | (unsigned)nb;
      if (pn < best) { best = pn; bestnb = nb; }
    }
    label[i] = (unsigned short)bestnb;
  }
  __syncthreads();
  for (int round = 0; round < 12; round++) {   // >= doubling per round; early exit
    bool changed = false;
    for (int i = tid; i < NPIX; i += NT) {
      unsigned short l = label[i];
      unsigned short l2 = label[l];
      if (l2 != l) { label[i] = l2; changed = true; }
    }
    if (changed) s_chg[round] = 1;
    __syncthreads();
    if (!s_chg[round]) break;                  // block-uniform
  }

  // --- phase 3: inter-basin edges deduped to min weight per basin pair ---
  const int pdr[4] = {1, 0, 1,  1};
  const int pdc[4] = {0, 1, 1, -1};
  const int npd = pass ? 2 : 4;
  for (int i = tid; i < NPIX; i += NT) {
    int r = i >> 6, cc = i & 63;
    unsigned la = label[i];
    unsigned ki = key32[i];
    for (int d = 0; d < npd; d++) {
      int rr = r + pdr[d], c2 = cc + pdc[d];
      if ((unsigned)rr >= 64u || (unsigned)c2 >= 64u) continue;
      int nb = (rr << 6) | c2;
      unsigned lb = label[nb];
      if (lb == la) continue;
      unsigned wkey = max(ki, key32[nb]);      // weight = max endpoint key
      unsigned pk = la < lb ? ((la << 12) | lb) : ((lb << 12) | la);
      unsigned h = (pk * 2654435761u) >> 20;
      while (true) {
        unsigned old = atomicCAS(&hkey[h], EMPTY, pk);
        if (old == EMPTY || old == pk) { atomicMin(&hval[h], wkey); break; }
        h = (h + 1) & (NPIX - 1);
      }
    }
  }
  __syncthreads();

  // --- phase 4: stage hash+keys+basin flags; ONE packed u64 scan (edges|basins);
  //     write edges, basin list, node records ---
  unsigned long long item[PPT];
  unsigned mykeys[PPT];
  int cnt = 0, bcnt = 0, bmask = 0;
  #pragma unroll
  for (int q = 0; q < PPT; q++) {
    int s = tid * PPT + q;
    unsigned pk = hkey[s];
    if (pk != EMPTY) item[cnt++] = (((unsigned long long)hval[s]) << 32) | pk;
  }
  #pragma unroll
  for (int t = 0; t < PPT; t++) {
    int i = tid + t * NT;
    mykeys[t] = key32[i];
    if (label[i] == (unsigned short)i) { bmask |= 1 << t; bcnt++; }
  }
  __syncthreads();                       // all reads of pool[0..56K) done
  unsigned long long inc2 = ((unsigned long long)cnt << 32) | (unsigned)bcnt;
  for (int off = 1; off < 64; off <<= 1) {   // intra-wave inclusive scan (both counts)
    unsigned long long v = __shfl_up(inc2, off);
    if (lane >= off) inc2 += v;
  }
  if (lane == 63) wred[wid] = inc2;
  __syncthreads();
  if (wid == 0) {                        // scan the 16 wave totals in wave 0
    unsigned long long wv = (lane < 16) ? wred[lane] : 0ull;
    for (int off = 1; off < 16; off <<= 1) {
      unsigned long long v = __shfl_up(wv, off);
      if (lane >= off) wv += v;
    }
    if (lane < 16) wred[16 + lane] = wv;
  }
  __syncthreads();
  const unsigned long long tot = wred[31];
  const int M = (int)(tot >> 32);
  const int NB = (int)(tot & 0xFFFFFFFFull);
  const unsigned long long wbase = (wid == 0) ? 0ull : wred[16 + wid - 1];
  const int base = (int)((wbase >> 32) + (inc2 >> 32)) - cnt;
  int bbase = (int)((wbase & 0xFFFFFFFFull) + (inc2 & 0xFFFFFFFFull)) - bcnt;
  __syncthreads();                       // wred consumed; pool writable
  for (int q = 0; q < cnt; q++) sbuf[base + q] = item[q];
  #pragma unroll
  for (int t = 0; t < PPT; t++) {
    int i = tid + t * NT;
    node[i] = (((unsigned long long)mykeys[t]) << 32) | (unsigned)i;  // singleton
    if (bmask & (1 << t)) blist[bbase++] = (unsigned short)i;
  }
  for (int i = M + tid; i < NPIX; i += NT) sbuf[i] = ~0ull;           // pad
  __syncthreads();

  // --- phase 5: sort edges ascending by weight key ---
  if (M <= 2048) {
    // Hybrid bitonic on 2048: j<64 via shfl_xor (no barrier); j in [64,512] via
    // ping-pong LDS (A=pool[0..2048), B=pool[2048..4096)); j=1024 in-thread.
    unsigned long long v0 = sbuf[tid];
    unsigned long long v1 = sbuf[tid + 1024];
    const int i0 = tid, i1 = tid + 1024;
    auto regstage = [&](int k, int j) {
      unsigned long long p0 = __shfl_xor(v0, j);
      unsigned long long p1 = __shfl_xor(v1, j);
      bool m0 = (((i0 & j) == 0) == ((i0 & k) == 0));
      bool m1 = (((i1 & j) == 0) == ((i1 & k) == 0));
      v0 = m0 ? (v0 < p0 ? v0 : p0) : (v0 > p0 ? v0 : p0);
      v1 = m1 ? (v1 < p1 ? v1 : p1) : (v1 > p1 ? v1 : p1);
    };
    int buf = 1;
    for (int k = 2; k <= 64; k <<= 1)
      for (int j = k >> 1; j >= 1; j >>= 1) regstage(k, j);
    for (int k = 128; k <= 2048; k <<= 1) {
      for (int j = k >> 1; j >= 64; j >>= 1) {
        if (j == 1024) {                 // partner is own other element; ascending
          if (v0 > v1) { unsigned long long t = v0; v0 = v1; v1 = t; }
        } else {
          unsigned long long* bp = pool + (buf ? 2048 : 0);
          bp[tid] = v0; bp[tid + 1024] = v1;
          __syncthreads();
          unsigned long long p0 = bp[tid ^ j];
          unsigned long long p1 = bp[(tid ^ j) + 1024];
          bool m0 = (((i0 & j) == 0) == ((i0 & k) == 0));
          bool m1 = (((i1 & j) == 0) == ((i1 & k) == 0));
          v0 = m0 ? (v0 < p0 ? v0 : p0) : (v0 > p0 ? v0 : p0);
          v1 = m1 ? (v1 < p1 ? v1 : p1) : (v1 > p1 ? v1 : p1);
          buf ^= 1;
        }
      }
      for (int j = 32; j >= 1; j >>= 1) regstage(k, j);
    }
    sbuf[tid] = v0; sbuf[tid + 1024] = v1;   // final: back to A for Kruskal
    __syncthreads();
  } else {
    // fallback: in-place bitonic on 4096 (never hit for this input shape)
    for (int k = 2; k <= NPIX; k <<= 1) {
      for (int j = k >> 1; j > 0; j >>= 1) {
        for (int i = tid; i < NPIX; i += NT) {
          int ixj = i ^ j;
          if (ixj > i) {
            unsigned long long va = sbuf[i], vb = sbuf[ixj];
            bool up = ((i & k) == 0);
            if ((va > vb) == up) { sbuf[i] = vb; sbuf[ixj] = va; }
          }
        }
        __syncthreads();
      }
    }
  }

  // --- phase 6: wave-parallel Kruskal (wave 0) with claim-based parallel commit.
  //     Round = claims -> winner test -> commits -> re-finds, as SEQUENTIAL
  //     re-converging regions with compiler barriers between them, so winners'
  //     node[] stores are in program order BEFORE losers' re-find loads (the
  //     R10 if/else layout let the compiler emit the loser region first ->
  //     stale roots -> corrupt forest). Basin-only flatten every 512 edges. ---
  double sumsq = 0.0;
  float maxp = 0.0f;
  int pcnt = 0;
  unsigned seq = 0;                      // monotone claim tag (no claim resets)
  const int ngroups = (M + 511) >> 9;
  for (int g = 0; g < ngroups; g++) {
    if (wid == 0) {
      for (int bb = 0; bb < 8; bb++) {
        const int e0 = (g << 9) + (bb << 6);
        if (e0 >= M) break;              // wave-uniform
        const int j = e0 + lane;
        const bool act = (j < M);
        unsigned long long e = act ? sbuf[j] : ~0ull;
        const unsigned wk = (unsigned)(e >> 32);
        const unsigned pk = (unsigned)(e & 0xFFFFFFu);
        unsigned xa = 0, xb = 0;
        unsigned long long recA = 0, recB = 0;
        bool pending = false;
        if (act) {
          xa = pk >> 12; xb = pk & 0xFFFu;
          recA = node[xa];
          recB = node[xb];               // finds' loads overlap across lanes
          while ((unsigned)recA != xa) { xa = (unsigned)recA; recA = node[xa]; }
          while ((unsigned)recB != xb) { xb = (unsigned)recB; recB = node[xb]; }
          pending = (xa != xb);
        }
        while (__ballot(pending)) {
          seq++;
          const unsigned myval = (seq << 6) | (63u - (unsigned)lane);
          // region 1: claims (smaller lane = earlier edge = higher priority)
          if (pending) {
            atomicMax(&claim[xa], myval);
            atomicMax(&claim[xb], myval);
          }
          memfence_compiler();
          // region 2: winner test (reads see ALL lanes' claims: lockstep order)
          bool winner = false;
          if (pending)
            winner = (claim[xa] == myval) & (claim[xb] == myval);
          memfence_compiler();
          // region 3: commits (winners pairwise root-disjoint -> commute)
          if (winner) {
            unsigned t_elder, t_young;
            unsigned long long t_yrec;
            if (recA < recB) { t_elder = xa; t_young = xb; t_yrec = recB; }
            else             { t_elder = xb; t_young = xa; t_yrec = recA; }
            const unsigned ky = (unsigned)(t_yrec >> 32);
            if (wk > ky) {               // strictly positive persistence
              float pers = kval(wk) - kval(ky);
              sumsq += (double)pers * (double)pers;
              maxp = fmaxf(maxp, pers);
              pcnt++;
            }
            node[t_young] = (t_yrec & 0xFFFFFFFF00000000ull) | t_elder;
            pending = false;
          }
          memfence_compiler();
          // region 4: losers re-find AFTER all commits of this round
          if (pending) {
            recA = node[xa]; recB = node[xb];
            while ((unsigned)recA != xa) { xa = (unsigned)recA; recA = node[xa]; }
            while ((unsigned)recB != xb) { xb = (unsigned)recB; recB = node[xb]; }
            pending = (xa != xb);
          }
        }
      }
    }
    __syncthreads();
    for (int i = tid; i < NB; i += NT) {     // flatten basins only (NB <= 2048)
      const int p0 = blist[i];
      unsigned long long rec = node[p0];
      unsigned px = (unsigned)rec;
      if (px == (unsigned)p0) continue;
      unsigned long long r2 = node[px];
      while ((unsigned)r2 != px) { px = (unsigned)r2; r2 = node[px]; }
      node[p0] = (rec & 0xFFFFFFFF00000000ull) | px;
    }
    __syncthreads();
  }
  if (wid == 0) {                        // reduce lane accumulators to lane 0
    for (int off = 32; off > 0; off >>= 1) {
      sumsq += __shfl_xor(sumsq, off);
      maxp = fmaxf(maxp, __shfl_xor(maxp, off));
      pcnt += __shfl_xor(pcnt, off);
    }
  }

  // --- phase 7: per-block contribution ---
  float contrib = 0.0f;
  if (tid == 0) {
    if (pass == 0) {
      const int nf0 = (c == 3) ? 2 : 1;      // TOPO H0: c1->1, c2->1, c3->2
      float vmin = kval(vmink);              // essential birth = global min
      if (nf0 == 1) {
        contrib = vmin * vmin + (float)sumsq;
      } else if (pcnt >= 1) {
        contrib = vmin * vmin + (1.0f - maxp) * (1.0f - maxp)
                + (float)(sumsq - (double)maxp * (double)maxp);
      } else {
        contrib = vmin * vmin + 1.0f;
      }
    } else {
      const int nf1 = (c == 2) ? 1 : 0;      // TOPO H1: c1->0, c2->1, c3->0
      if (nf1 == 0) contrib = (float)sumsq;
      else contrib = (pcnt >= 1)
        ? ((1.0f - maxp) * (1.0f - maxp) + (float)(sumsq - (double)maxp * (double)maxp))
        : 1.0f;
    }
    contrib *= 0.25f;                        // / B, B = 4
    if (use_ws) {
      // publish (value<<32 | magic) in one device-scope atomic — no fence needed
      atomicExch(&ws64[blk],
                 (((unsigned long long)__float_as_uint(contrib)) << 32) | FLAGMAGIC);
    } else {
      atomicAdd(out, contrib);               // out pre-zeroed by ph_zero_kernel
    }
  }
  // --- block 0 wave 0: gather all 24 contributions, write out ---
  if (use_ws && blk == 0 && wid == 0) {
    float v = 0.0f;
    if (lane < 24) {
      while (true) {
        unsigned long long r = atomicAdd(&ws64[lane], 0ull);  // device-coherent read
        if ((unsigned)r == FLAGMAGIC) { v = __uint_as_float((unsigned)(r >> 32)); break; }
      }
    }
    for (int off = 32; off > 0; off >>= 1) v += __shfl_xor(v, off);
    if (lane == 0) out[0] = v;
  }
}

extern "C" void kernel_launch(void* const* d_in, const int* in_sizes, int n_in,
                              void* d_out, int out_size, void* d_ws, size_t ws_size,
                              hipStream_t stream) {
  const float* x = (const float*)d_in[0];
  float* out = (float*)d_out;
  if (ws_size >= 24 * sizeof(unsigned long long)) {
    ph_pass_kernel<<<24, NT, 0, stream>>>(x, out, (unsigned long long*)d_ws, 1);
  } else {
    ph_zero_kernel<<<1, 1, 0, stream>>>(out);
    ph_pass_kernel<<<24, NT, 0, stream>>>(x, out, nullptr, 0);
  }
}